// Round 3
// baseline (1006.862 us; speedup 1.0000x reference)
//
#include <hip/hip_runtime.h>
#include <hip/hip_bf16.h>

// Problem constants
#define S_LEN 1024
#define HID   4096
#define NH    32
#define NKV   8
#define HD    128
#define MIN_IDX 4
#define AO_COLS 4096        // NH*HD
#define HEAD_STRIDE 131072  // S_LEN*HD

typedef __attribute__((ext_vector_type(8))) short short8;
typedef __attribute__((ext_vector_type(4))) float f32x4;

__device__ __forceinline__ unsigned short f2bf(float f) {
  union { float f; unsigned u; } v; v.f = f;
  unsigned r = v.u + 0x7FFFu + ((v.u >> 16) & 1u);   // RNE
  return (unsigned short)(r >> 16);
}
__device__ __forceinline__ float bf2f(unsigned short h) {
  union { unsigned u; float f; } v; v.u = ((unsigned)h) << 16;
  return v.f;
}
__device__ __forceinline__ unsigned pk2(float a, float b) {
  union { __hip_bfloat162 h; unsigned u; } c;
  c.h = __float22bfloat162_rn(make_float2(a, b));    // v_cvt_pk_bf16_f32
  return c.u;
}
__device__ __forceinline__ short8 pack8(float4 a, float4 b) {
  union { short8 s; unsigned u[4]; } r;
  r.u[0] = pk2(a.x, a.y); r.u[1] = pk2(a.z, a.w);
  r.u[2] = pk2(b.x, b.y); r.u[3] = pk2(b.z, b.w);
  return r.s;
}
// float -> order-preserving uint
__device__ __forceinline__ unsigned ordf(float f) {
  union { float f; int i; } v; v.f = f;
  return (unsigned)(v.i ^ ((v.i >> 31) | 0x80000000));
}
__device__ __forceinline__ int wave_sum_i(int v) {
  #pragma unroll
  for (int m = 32; m >= 1; m >>= 1) v += __shfl_xor(v, m);
  return v;
}
__device__ __forceinline__ float wave_sum_f(float v) {
  #pragma unroll
  for (int m = 32; m >= 1; m >>= 1) v += __shfl_xor(v, m);
  return v;
}
__device__ __forceinline__ float wave_max_f(float v) {
  #pragma unroll
  for (int m = 32; m >= 1; m >>= 1) v = fmaxf(v, __shfl_xor(v, m));
  return v;
}

// ---------------------------------------------------------------------------
// Kernel 1: QKV projection (NT gemm), epilogue writes bf16 directly:
//   Q tiles (nt<32)  -> Qraw[h][s][d]
//   K tiles (32..39) -> Kraw[kvh][s][d]
//   V tiles (40..47) -> Vt[kvh][d][s]   (pre-transposed, ushort4 stores)
// ---------------------------------------------------------------------------
__global__ __launch_bounds__(256) void gemm_qkv_k(
    const float* __restrict__ X, const float* __restrict__ Wq,
    const float* __restrict__ Wk, const float* __restrict__ Wv,
    unsigned short* __restrict__ Qraw, unsigned short* __restrict__ Kraw,
    unsigned short* __restrict__ Vt)
{
  __shared__ unsigned short As[128][40];   // stride 40 shorts = 80 B (16B-mult)
  __shared__ unsigned short Bs[128][40];
  const int nt = blockIdx.x;               // 0..47
  const int n0 = nt * 128;
  const int m0 = blockIdx.y * 128;
  const float* Bp;
  if (n0 < 4096)      Bp = Wq + (size_t)n0 * HID;
  else if (n0 < 5120) Bp = Wk + (size_t)(n0 - 4096) * HID;
  else                Bp = Wv + (size_t)(n0 - 5120) * HID;

  const int t = threadIdx.x;
  const int w = t >> 6, lane = t & 63;
  const int wm = w >> 1, wn = w & 1;
  const int mcol = lane & 15, quad = lane >> 4;
  const int srow = t >> 1;
  const int sseg = (t & 1) * 16;

  f32x4 acc[4][4];
  #pragma unroll
  for (int i = 0; i < 4; i++)
    #pragma unroll
    for (int j = 0; j < 4; j++) acc[i][j] = (f32x4){0.f, 0.f, 0.f, 0.f};

  for (int k0 = 0; k0 < HID; k0 += 32) {
    const float* ga = X  + (size_t)(m0 + srow) * HID + k0 + sseg;
    const float* gb = Bp + (size_t)srow * HID + k0 + sseg;
    float4 a0 = ((const float4*)ga)[0], a1 = ((const float4*)ga)[1];
    float4 a2 = ((const float4*)ga)[2], a3 = ((const float4*)ga)[3];
    float4 b0 = ((const float4*)gb)[0], b1 = ((const float4*)gb)[1];
    float4 b2 = ((const float4*)gb)[2], b3 = ((const float4*)gb)[3];
    *(short8*)&As[srow][sseg]     = pack8(a0, a1);
    *(short8*)&As[srow][sseg + 8] = pack8(a2, a3);
    *(short8*)&Bs[srow][sseg]     = pack8(b0, b1);
    *(short8*)&Bs[srow][sseg + 8] = pack8(b2, b3);
    __syncthreads();
    short8 af[4], bf[4];
    #pragma unroll
    for (int i = 0; i < 4; i++) af[i] = *(const short8*)&As[wm*64 + i*16 + mcol][quad*8];
    #pragma unroll
    for (int j = 0; j < 4; j++) bf[j] = *(const short8*)&Bs[wn*64 + j*16 + mcol][quad*8];
    #pragma unroll
    for (int i = 0; i < 4; i++)
      #pragma unroll
      for (int j = 0; j < 4; j++)
        acc[i][j] = __builtin_amdgcn_mfma_f32_16x16x32_bf16(af[i], bf[j], acc[i][j], 0, 0, 0);
    __syncthreads();
  }

  if (nt < 40) {
    unsigned short* dst = (nt < 32) ? (Qraw + (size_t)nt * HEAD_STRIDE)
                                    : (Kraw + (size_t)(nt - 32) * HEAD_STRIDE);
    #pragma unroll
    for (int i = 0; i < 4; i++) {
      const int rb = m0 + wm*64 + i*16 + quad*4;   // C/D: row=(lane>>4)*4+reg
      #pragma unroll
      for (int j = 0; j < 4; j++) {
        const int d = wn*64 + j*16 + mcol;         // col=lane&15
        #pragma unroll
        for (int r = 0; r < 4; r++)
          dst[(size_t)(rb + r) * HD + d] = f2bf(acc[i][j][r]);
      }
    }
  } else {
    unsigned short* dst = Vt + (size_t)(nt - 40) * HEAD_STRIDE;
    #pragma unroll
    for (int i = 0; i < 4; i++) {
      const int rb = m0 + wm*64 + i*16 + quad*4;   // 4 consecutive s per lane
      #pragma unroll
      for (int j = 0; j < 4; j++) {
        const int d = wn*64 + j*16 + mcol;
        ushort4 v4;
        v4.x = f2bf(acc[i][j][0]); v4.y = f2bf(acc[i][j][1]);
        v4.z = f2bf(acc[i][j][2]); v4.w = f2bf(acc[i][j][3]);
        *(ushort4*)(dst + (size_t)d * S_LEN + rb) = v4;
      }
    }
  }
}

// ---------------------------------------------------------------------------
// Kernel 2: RoPE in-place on bf16 Q and K. One wave per (head_row, s).
// ---------------------------------------------------------------------------
__global__ __launch_bounds__(256) void rope_qk_k(
    const int* __restrict__ pos_ids,
    unsigned short* __restrict__ Qraw, unsigned short* __restrict__ Kraw)
{
  const int w = threadIdx.x >> 6, lane = threadIdx.x & 63;
  const int gw = blockIdx.x * 4 + w;           // 0 .. (NH+NKV)*S-1
  const int hidx = gw >> 10;
  const int s = gw & 1023;
  const float pos = (float)pos_ids[s];
  const float invf = powf(10000.0f, -(float)lane * (1.0f / 64.0f));
  float sn, cs;
  sincosf(pos * invf, &sn, &cs);
  unsigned short* base = (hidx < NH)
      ? (Qraw + (size_t)hidx * HEAD_STRIDE + (size_t)s * HD)
      : (Kraw + (size_t)(hidx - NH) * HEAD_STRIDE + (size_t)s * HD);
  const float x0 = bf2f(base[lane]), x1 = bf2f(base[lane + 64]);
  base[lane]      = f2bf(x0 * cs - x1 * sn);
  base[lane + 64] = f2bf(x1 * cs + x0 * sn);
}

// ---------------------------------------------------------------------------
// Kernel 3: fused sparse attention. One block = (head, 16-query rows).
// Phase 1: scores (bf16 MFMA) -> LDS fp32 [16][1028].
// Phase 2: per-row radix-select k-th largest score (k=(q+1)/2), exact
//          index-order tie handling, + sinks j<4, then softmax.
// Phase 3: PV via bf16 MFMA, write attn-out bf16 [S][NH*HD].
// ---------------------------------------------------------------------------
#define SCS 1028
__global__ __launch_bounds__(256) void attn_k(
    const unsigned short* __restrict__ Qb, const unsigned short* __restrict__ Kb,
    const unsigned short* __restrict__ Vt, unsigned short* __restrict__ AO)
{
  __shared__ float sc[16][SCS];                // 65792 B
  __shared__ unsigned short kv[128][136];      // 34816 B
  __shared__ int hist[4][256];
  __shared__ float rowinv[16];
  const int rb = blockIdx.x, h = blockIdx.y;
  const int kvh = h >> 2;                      // GROUPS=4
  const int q0 = rb * 16;
  const int kt_max = (q0 + 16 + 127) >> 7;
  const int ktot = kt_max * 128;
  const int t = threadIdx.x, w = t >> 6, lane = t & 63;
  const int mcol = lane & 15, quad = lane >> 4;
  const float scale = 0.08838834764831845f;    // 1/sqrt(128)

  // Q fragments (A operand: m=lane&15, k=quad*8+j)
  short8 aq[4];
  {
    const unsigned short* qrow = Qb + ((size_t)h * S_LEN + q0 + mcol) * HD + quad * 8;
    #pragma unroll
    for (int kk = 0; kk < 4; kk++) aq[kk] = *(const short8*)(qrow + kk * 32);
  }

  // ---- Phase 1: scores ----
  for (int kt = 0; kt < kt_max; kt++) {
    {
      // each thread owns 64 shorts (128 B) of a 128-short K row: 8x uint4
      const int row = t >> 1, seg = (t & 1) * 64;
      const unsigned short* src = Kb + ((size_t)kvh * S_LEN + kt * 128 + row) * HD + seg;
      unsigned short* d = &kv[row][seg];
      #pragma unroll
      for (int ii = 0; ii < 8; ii++)
        ((uint4*)d)[ii] = ((const uint4*)src)[ii];
    }
    __syncthreads();
    #pragma unroll
    for (int g2 = 0; g2 < 2; g2++) {
      const int g = w * 2 + g2;
      f32x4 d4 = {0.f, 0.f, 0.f, 0.f};
      #pragma unroll
      for (int kk = 0; kk < 4; kk++) {
        short8 bfr = *(const short8*)&kv[g*16 + mcol][kk*32 + quad*8];
        d4 = __builtin_amdgcn_mfma_f32_16x16x32_bf16(aq[kk], bfr, d4, 0, 0, 0);
      }
      const int col = kt * 128 + g * 16 + mcol;
      #pragma unroll
      for (int r = 0; r < 4; r++) sc[quad*4 + r][col] = d4[r] * scale;
    }
    __syncthreads();
  }

  // ---- Phase 2: selection + softmax (wave w owns rows w*4 .. w*4+3) ----
  // All barriers below are in block-uniform control flow (fixed trip counts).
  for (int i = 0; i < 4; i++) {
    const int r = w * 4 + i;
    const int q = q0 + r;
    const int L = q + 1;
    int ksel = (q + 1) >> 1; if (ksel < 1) ksel = 1;

    unsigned prefix = 0, msk = 0;
    int krem = ksel;
    #pragma unroll
    for (int shift = 24; shift >= 0; shift -= 8) {
      __syncthreads();
      for (int b = lane; b < 256; b += 64) hist[w][b] = 0;
      __syncthreads();
      for (int j = lane; j < L; j += 64) {
        unsigned u = ordf(sc[r][j]);
        if ((u & msk) == prefix) atomicAdd(&hist[w][(u >> shift) & 255], 1);
      }
      __syncthreads();
      int c[4], lsum = 0;
      #pragma unroll
      for (int j2 = 0; j2 < 4; j2++) { c[j2] = hist[w][255 - lane*4 - j2]; lsum += c[j2]; }
      int x = lsum;
      #pragma unroll
      for (int d2 = 1; d2 < 64; d2 <<= 1) { int y = __shfl_up(x, d2); if (lane >= d2) x += y; }
      int run = x - lsum;
      int fbin = -1, fbefore = 0;
      #pragma unroll
      for (int j2 = 0; j2 < 4; j2++) {
        if (fbin < 0 && run < krem && run + c[j2] >= krem) { fbin = 255 - lane*4 - j2; fbefore = run; }
        run += c[j2];
      }
      unsigned long long bal = __ballot(fbin >= 0);
      int bin = 0, before = 0;
      if (bal != 0ull) {                       // wave-uniform branch
        const int srcl = __ffsll((unsigned long long)bal) - 1;
        bin = __shfl(fbin, srcl);
        before = __shfl(fbefore, srcl);
        if (bin < 0) bin = 0;
      }
      krem -= before; if (krem < 1) krem = 1;
      prefix |= ((unsigned)bin) << shift;
      msk |= 0xFFu << shift;
    }
    const unsigned tau = prefix;

    int cg = 0;
    for (int j = lane; j < L; j += 64) cg += (ordf(sc[r][j]) > tau) ? 1 : 0;
    const int mgt = wave_sum_i(cg);
    const int tie_budget = ksel - mgt;         // >=1 when tau is exact

    // keep-mask pass (16 bits per lane), running max over kept
    unsigned keep = 0;
    int tiebase = 0, it = 0;
    float mx = -3.0e38f;
    for (int j0 = 0; j0 < L; j0 += 64, it++) {
      const int j = j0 + lane;
      const bool act = j < L;
      float s = 0.f; unsigned u = 0;
      if (act) { s = sc[r][j]; u = ordf(s); }
      const bool eq = act && (u == tau);
      const unsigned long long bal = __ballot(eq);
      const int trank = tiebase + (int)__popcll(bal & ((1ull << lane) - 1ull));
      tiebase += (int)__popcll(bal);
      const bool kept = act && ((u > tau) || (eq && trank < tie_budget) || (j < MIN_IDX));
      if (kept) { keep |= (1u << it); mx = fmaxf(mx, s); }
    }
    mx = wave_max_f(mx);                       // sink j=0 always kept => finite
    float ssum = 0.f;
    it = 0;
    for (int j0 = 0; j0 < ktot; j0 += 64, it++) {
      const int j = j0 + lane;                 // < ktot (ktot multiple of 128)
      float e = 0.f;
      if ((keep >> it) & 1u) e = __expf(sc[r][j] - mx);
      sc[r][j] = e;
      ssum += e;
    }
    ssum = wave_sum_f(ssum);
    if (lane == 0) rowinv[r] = 1.f / fmaxf(ssum, 1e-30f);
  }
  __syncthreads();

  // ---- Phase 3: PV ----
  f32x4 opv[2];
  opv[0] = (f32x4){0.f,0.f,0.f,0.f}; opv[1] = (f32x4){0.f,0.f,0.f,0.f};
  const float inv = rowinv[mcol];
  for (int kt = 0; kt < kt_max; kt++) {
    {
      // each thread owns 64 shorts (128 B) of a 128-key V row: 8x uint4
      const int d = t >> 1, seg = (t & 1) * 64;
      const unsigned short* src = Vt + ((size_t)kvh * HD + d) * S_LEN + kt * 128 + seg;
      unsigned short* dd = &kv[d][seg];
      #pragma unroll
      for (int ii = 0; ii < 8; ii++)
        ((uint4*)dd)[ii] = ((const uint4*)src)[ii];
    }
    __syncthreads();
    #pragma unroll
    for (int kb = 0; kb < 4; kb++) {
      const float* prow = &sc[mcol][kt*128 + kb*32 + quad*8];
      float4 p0 = *(const float4*)prow;
      float4 p1 = *(const float4*)(prow + 4);
      union { short8 s; unsigned u[4]; } af;
      af.u[0] = pk2(p0.x * inv, p0.y * inv);
      af.u[1] = pk2(p0.z * inv, p0.w * inv);
      af.u[2] = pk2(p1.x * inv, p1.y * inv);
      af.u[3] = pk2(p1.z * inv, p1.w * inv);
      #pragma unroll
      for (int n2 = 0; n2 < 2; n2++) {
        short8 bfr = *(const short8*)&kv[(w*2 + n2)*16 + mcol][kb*32 + quad*8];
        opv[n2] = __builtin_amdgcn_mfma_f32_16x16x32_bf16(af.s, bfr, opv[n2], 0, 0, 0);
      }
    }
    __syncthreads();
  }
  #pragma unroll
  for (int n2 = 0; n2 < 2; n2++) {
    const int col = h * HD + (w*2 + n2) * 16 + mcol;
    #pragma unroll
    for (int r2 = 0; r2 < 4; r2++) {
      const int row = q0 + quad*4 + r2;
      AO[(size_t)row * AO_COLS + col] = f2bf(opv[n2][r2]);
    }
  }
}

// ---------------------------------------------------------------------------
// Kernel 4: output projection.  out[s][n] = sum_o AO[s][o] * Wo[n][o]
// ---------------------------------------------------------------------------
__global__ __launch_bounds__(256) void gemm_out_k(
    const unsigned short* __restrict__ A, const float* __restrict__ Wo,
    float* __restrict__ Out)
{
  __shared__ unsigned short As[128][40];
  __shared__ unsigned short Bs[128][40];
  const int n0 = blockIdx.x * 128;
  const int m0 = blockIdx.y * 128;
  const float* Bp = Wo + (size_t)n0 * AO_COLS;

  const int t = threadIdx.x;
  const int w = t >> 6, lane = t & 63;
  const int wm = w >> 1, wn = w & 1;
  const int mcol = lane & 15, quad = lane >> 4;
  const int srow = t >> 1;
  const int sseg = (t & 1) * 16;

  f32x4 acc[4][4];
  #pragma unroll
  for (int i = 0; i < 4; i++)
    #pragma unroll
    for (int j = 0; j < 4; j++) acc[i][j] = (f32x4){0.f, 0.f, 0.f, 0.f};

  for (int k0 = 0; k0 < AO_COLS; k0 += 32) {
    const unsigned short* ga = A + (size_t)(m0 + srow) * AO_COLS + k0 + sseg;
    uint4 ua0 = ((const uint4*)ga)[0], ua1 = ((const uint4*)ga)[1];
    const float* gb = Bp + (size_t)srow * AO_COLS + k0 + sseg;
    float4 b0 = ((const float4*)gb)[0], b1 = ((const float4*)gb)[1];
    float4 b2 = ((const float4*)gb)[2], b3 = ((const float4*)gb)[3];
    *(uint4*)&As[srow][sseg]      = ua0;
    *(uint4*)&As[srow][sseg + 8]  = ua1;
    *(short8*)&Bs[srow][sseg]     = pack8(b0, b1);
    *(short8*)&Bs[srow][sseg + 8] = pack8(b2, b3);
    __syncthreads();
    short8 af[4], bf[4];
    #pragma unroll
    for (int i = 0; i < 4; i++) af[i] = *(const short8*)&As[wm*64 + i*16 + mcol][quad*8];
    #pragma unroll
    for (int j = 0; j < 4; j++) bf[j] = *(const short8*)&Bs[wn*64 + j*16 + mcol][quad*8];
    #pragma unroll
    for (int i = 0; i < 4; i++)
      #pragma unroll
      for (int j = 0; j < 4; j++)
        acc[i][j] = __builtin_amdgcn_mfma_f32_16x16x32_bf16(af[i], bf[j], acc[i][j], 0, 0, 0);
    __syncthreads();
  }
  #pragma unroll
  for (int i = 0; i < 4; i++) {
    const int rb = m0 + wm*64 + i*16 + quad*4;
    #pragma unroll
    for (int j = 0; j < 4; j++) {
      const int col = n0 + wn*64 + j*16 + mcol;
      #pragma unroll
      for (int r = 0; r < 4; r++)
        Out[(size_t)(rb + r) * HID + col] = acc[i][j][r];
    }
  }
}

// ---------------------------------------------------------------------------
// Workspace layout (20,971,520 bytes total):
//   [0)          Qraw bf16 [NH][S][HD]          8,388,608
//   [+8388608)   Kraw bf16 [NKV][S][HD]         2,097,152
//   [+10485760)  Vt   bf16 [NKV][HD][S]         2,097,152
//   [+12582912)  AO   bf16 [S][NH*HD]           8,388,608
// ---------------------------------------------------------------------------
extern "C" void kernel_launch(void* const* d_in, const int* in_sizes, int n_in,
                              void* d_out, int out_size, void* d_ws, size_t ws_size,
                              hipStream_t stream) {
  (void)in_sizes; (void)n_in; (void)out_size; (void)ws_size;
  const float* X   = (const float*)d_in[0];
  const int*   pos = (const int*)d_in[1];
  const float* Wq  = (const float*)d_in[2];
  const float* Wk  = (const float*)d_in[3];
  const float* Wv  = (const float*)d_in[4];
  const float* Wo  = (const float*)d_in[5];
  float* out = (float*)d_out;

  char* ws = (char*)d_ws;
  unsigned short* Qraw = (unsigned short*)ws;
  unsigned short* Kraw = (unsigned short*)(ws + 8388608);
  unsigned short* Vt   = (unsigned short*)(ws + 10485760);
  unsigned short* AO   = (unsigned short*)(ws + 12582912);

  gemm_qkv_k<<<dim3(48, 8),  dim3(256), 0, stream>>>(X, Wq, Wk, Wv, Qraw, Kraw, Vt);
  rope_qk_k <<<dim3(10240),  dim3(256), 0, stream>>>(pos, Qraw, Kraw);
  attn_k    <<<dim3(64, 32), dim3(256), 0, stream>>>(Qraw, Kraw, Vt, AO);
  gemm_out_k<<<dim3(32, 8),  dim3(256), 0, stream>>>(AO, Wo, out);
}

// Round 4
// 723.918 us; speedup vs baseline: 1.3909x; 1.3909x over previous
//
#include <hip/hip_runtime.h>
#include <hip/hip_bf16.h>

// Problem constants
#define S_LEN 1024
#define HID   4096
#define NH    32
#define NKV   8
#define HD    128
#define MIN_IDX 4
#define AO_COLS 4096        // NH*HD
#define HEAD_STRIDE 131072  // S_LEN*HD

typedef __attribute__((ext_vector_type(8))) short short8;
typedef __attribute__((ext_vector_type(4))) float f32x4;

__device__ __forceinline__ unsigned short f2bf(float f) {
  union { float f; unsigned u; } v; v.f = f;
  unsigned r = v.u + 0x7FFFu + ((v.u >> 16) & 1u);   // RNE
  return (unsigned short)(r >> 16);
}
__device__ __forceinline__ float bf2f(unsigned short h) {
  union { unsigned u; float f; } v; v.u = ((unsigned)h) << 16;
  return v.f;
}
__device__ __forceinline__ unsigned pk2(float a, float b) {
  union { __hip_bfloat162 h; unsigned u; } c;
  c.h = __float22bfloat162_rn(make_float2(a, b));    // v_cvt_pk_bf16_f32
  return c.u;
}
__device__ __forceinline__ short8 pack8(float4 a, float4 b) {
  union { short8 s; unsigned u[4]; } r;
  r.u[0] = pk2(a.x, a.y); r.u[1] = pk2(a.z, a.w);
  r.u[2] = pk2(b.x, b.y); r.u[3] = pk2(b.z, b.w);
  return r.s;
}
// float -> order-preserving uint, and inverse
__device__ __forceinline__ unsigned ordf(float f) {
  union { float f; int i; } v; v.f = f;
  return (unsigned)(v.i ^ ((v.i >> 31) | 0x80000000));
}
__device__ __forceinline__ float iordf(unsigned u) {
  union { int i; float f; } v;
  v.i = (u & 0x80000000u) ? (int)(u ^ 0x80000000u) : (int)~u;
  return v.f;
}
__device__ __forceinline__ int wave_sum_i(int v) {
  #pragma unroll
  for (int m = 32; m >= 1; m >>= 1) v += __shfl_xor(v, m);
  return v;
}
__device__ __forceinline__ float wave_sum_f(float v) {
  #pragma unroll
  for (int m = 32; m >= 1; m >>= 1) v += __shfl_xor(v, m);
  return v;
}
__device__ __forceinline__ float wave_max_f(float v) {
  #pragma unroll
  for (int m = 32; m >= 1; m >>= 1) v = fmaxf(v, __shfl_xor(v, m));
  return v;
}
// wave-local LDS fence: hist[w] is wave-private, so no block barrier needed.
__device__ __forceinline__ void wave_lds_fence() {
  __builtin_amdgcn_s_waitcnt(0);        // vmcnt(0) expcnt(0) lgkmcnt(0)
  __builtin_amdgcn_wave_barrier();      // stop compiler reordering
}

// ---------------------------------------------------------------------------
// Kernel 1: QKV projection (NT gemm), epilogue writes bf16 directly:
//   Q tiles (nt<32)  -> Qraw[h][s][d]
//   K tiles (32..39) -> Kraw[kvh][s][d]
//   V tiles (40..47) -> Vt[kvh][d][s]   (pre-transposed, ushort4 stores)
// ---------------------------------------------------------------------------
__global__ __launch_bounds__(256) void gemm_qkv_k(
    const float* __restrict__ X, const float* __restrict__ Wq,
    const float* __restrict__ Wk, const float* __restrict__ Wv,
    unsigned short* __restrict__ Qraw, unsigned short* __restrict__ Kraw,
    unsigned short* __restrict__ Vt)
{
  __shared__ unsigned short As[128][40];   // stride 40 shorts = 80 B (16B-mult)
  __shared__ unsigned short Bs[128][40];
  const int nt = blockIdx.x;               // 0..47
  const int n0 = nt * 128;
  const int m0 = blockIdx.y * 128;
  const float* Bp;
  if (n0 < 4096)      Bp = Wq + (size_t)n0 * HID;
  else if (n0 < 5120) Bp = Wk + (size_t)(n0 - 4096) * HID;
  else                Bp = Wv + (size_t)(n0 - 5120) * HID;

  const int t = threadIdx.x;
  const int w = t >> 6, lane = t & 63;
  const int wm = w >> 1, wn = w & 1;
  const int mcol = lane & 15, quad = lane >> 4;
  const int srow = t >> 1;
  const int sseg = (t & 1) * 16;

  f32x4 acc[4][4];
  #pragma unroll
  for (int i = 0; i < 4; i++)
    #pragma unroll
    for (int j = 0; j < 4; j++) acc[i][j] = (f32x4){0.f, 0.f, 0.f, 0.f};

  for (int k0 = 0; k0 < HID; k0 += 32) {
    const float* ga = X  + (size_t)(m0 + srow) * HID + k0 + sseg;
    const float* gb = Bp + (size_t)srow * HID + k0 + sseg;
    float4 a0 = ((const float4*)ga)[0], a1 = ((const float4*)ga)[1];
    float4 a2 = ((const float4*)ga)[2], a3 = ((const float4*)ga)[3];
    float4 b0 = ((const float4*)gb)[0], b1 = ((const float4*)gb)[1];
    float4 b2 = ((const float4*)gb)[2], b3 = ((const float4*)gb)[3];
    *(short8*)&As[srow][sseg]     = pack8(a0, a1);
    *(short8*)&As[srow][sseg + 8] = pack8(a2, a3);
    *(short8*)&Bs[srow][sseg]     = pack8(b0, b1);
    *(short8*)&Bs[srow][sseg + 8] = pack8(b2, b3);
    __syncthreads();
    short8 af[4], bf[4];
    #pragma unroll
    for (int i = 0; i < 4; i++) af[i] = *(const short8*)&As[wm*64 + i*16 + mcol][quad*8];
    #pragma unroll
    for (int j = 0; j < 4; j++) bf[j] = *(const short8*)&Bs[wn*64 + j*16 + mcol][quad*8];
    #pragma unroll
    for (int i = 0; i < 4; i++)
      #pragma unroll
      for (int j = 0; j < 4; j++)
        acc[i][j] = __builtin_amdgcn_mfma_f32_16x16x32_bf16(af[i], bf[j], acc[i][j], 0, 0, 0);
    __syncthreads();
  }

  if (nt < 40) {
    unsigned short* dst = (nt < 32) ? (Qraw + (size_t)nt * HEAD_STRIDE)
                                    : (Kraw + (size_t)(nt - 32) * HEAD_STRIDE);
    #pragma unroll
    for (int i = 0; i < 4; i++) {
      const int rb = m0 + wm*64 + i*16 + quad*4;   // C/D: row=(lane>>4)*4+reg
      #pragma unroll
      for (int j = 0; j < 4; j++) {
        const int d = wn*64 + j*16 + mcol;         // col=lane&15
        #pragma unroll
        for (int r = 0; r < 4; r++)
          dst[(size_t)(rb + r) * HD + d] = f2bf(acc[i][j][r]);
      }
    }
  } else {
    unsigned short* dst = Vt + (size_t)(nt - 40) * HEAD_STRIDE;
    #pragma unroll
    for (int i = 0; i < 4; i++) {
      const int rb = m0 + wm*64 + i*16 + quad*4;   // 4 consecutive s per lane
      #pragma unroll
      for (int j = 0; j < 4; j++) {
        const int d = wn*64 + j*16 + mcol;
        ushort4 v4;
        v4.x = f2bf(acc[i][j][0]); v4.y = f2bf(acc[i][j][1]);
        v4.z = f2bf(acc[i][j][2]); v4.w = f2bf(acc[i][j][3]);
        *(ushort4*)(dst + (size_t)d * S_LEN + rb) = v4;
      }
    }
  }
}

// ---------------------------------------------------------------------------
// Kernel 2: RoPE in-place on bf16 Q and K. One wave per (head_row, s).
// ---------------------------------------------------------------------------
__global__ __launch_bounds__(256) void rope_qk_k(
    const int* __restrict__ pos_ids,
    unsigned short* __restrict__ Qraw, unsigned short* __restrict__ Kraw)
{
  const int w = threadIdx.x >> 6, lane = threadIdx.x & 63;
  const int gw = blockIdx.x * 4 + w;           // 0 .. (NH+NKV)*S-1
  const int hidx = gw >> 10;
  const int s = gw & 1023;
  const float pos = (float)pos_ids[s];
  const float invf = powf(10000.0f, -(float)lane * (1.0f / 64.0f));
  float sn, cs;
  sincosf(pos * invf, &sn, &cs);
  unsigned short* base = (hidx < NH)
      ? (Qraw + (size_t)hidx * HEAD_STRIDE + (size_t)s * HD)
      : (Kraw + (size_t)(hidx - NH) * HEAD_STRIDE + (size_t)s * HD);
  const float x0 = bf2f(base[lane]), x1 = bf2f(base[lane + 64]);
  base[lane]      = f2bf(x0 * cs - x1 * sn);
  base[lane + 64] = f2bf(x1 * cs + x0 * sn);
}

// ---------------------------------------------------------------------------
// Kernel 3: fused sparse attention. One block = (head, 16-query rows).
//  - No K/V LDS staging: B-fragments read directly from global (L2-resident,
//    K+V = 4 MB total, reused 256x). LDS ~70 KB -> 2 blocks/CU.
//  - Phase 2 runs from a register-cached score row (fixed 16-wide unroll),
//    wave-private histograms, zero block barriers inside.
//  - Exactly 2 __syncthreads per block.
// ---------------------------------------------------------------------------
#define SCS 1028
__global__ __launch_bounds__(256) void attn_k(
    const unsigned short* __restrict__ Qb, const unsigned short* __restrict__ Kb,
    const unsigned short* __restrict__ Vt, unsigned short* __restrict__ AO)
{
  __shared__ float sc[16][SCS];                // 65792 B
  __shared__ int hist[4][256];                 // 4096 B (wave-private rows)
  __shared__ float rowinv[16];
  const int rb = (int)gridDim.x - 1 - (int)blockIdx.x;  // heavy blocks first
  const int h = blockIdx.y;
  const int kvh = h >> 2;                      // GROUPS=4
  const int q0 = rb * 16;
  const int kt_max = (q0 + 16 + 127) >> 7;
  const int t = threadIdx.x, w = t >> 6, lane = t & 63;
  const int mcol = lane & 15, quad = lane >> 4;
  const float scale = 0.08838834764831845f;    // 1/sqrt(128)

  const unsigned short* Kh = Kb + (size_t)kvh * HEAD_STRIDE;  // [s][d]
  const unsigned short* Vh = Vt + (size_t)kvh * HEAD_STRIDE;  // [d][s]

  // Q fragments (A operand: m=lane&15, k=quad*8+j)
  short8 aq[4];
  {
    const unsigned short* qrow = Qb + ((size_t)h * S_LEN + q0 + mcol) * HD + quad * 8;
    #pragma unroll
    for (int kk = 0; kk < 4; kk++) aq[kk] = *(const short8*)(qrow + kk * 32);
  }

  // ---- Phase 1: scores (K fragments direct from global) ----
  for (int kt = 0; kt < kt_max; kt++) {
    #pragma unroll
    for (int g2 = 0; g2 < 2; g2++) {
      const int g = w * 2 + g2;
      const int key = kt * 128 + g * 16 + mcol;
      const unsigned short* krow = Kh + (size_t)key * HD + quad * 8;
      f32x4 d4 = {0.f, 0.f, 0.f, 0.f};
      #pragma unroll
      for (int kk = 0; kk < 4; kk++) {
        short8 bfr = *(const short8*)(krow + kk * 32);
        d4 = __builtin_amdgcn_mfma_f32_16x16x32_bf16(aq[kk], bfr, d4, 0, 0, 0);
      }
      const int col = kt * 128 + g * 16 + mcol;
      #pragma unroll
      for (int r = 0; r < 4; r++) sc[quad*4 + r][col] = d4[r] * scale;
    }
  }
  __syncthreads();

  // ---- Phase 2: selection + softmax (wave w owns rows w*4 .. w*4+3) ----
  for (int i = 0; i < 4; i++) {
    const int r = w * 4 + i;
    const int q = q0 + r;
    const int L = q + 1;
    int ksel = L >> 1; if (ksel < 1) ksel = 1;

    // cache row in registers (order-preserving uints); j>=L entries excluded
    unsigned uv[16];
    #pragma unroll
    for (int c = 0; c < 16; c++) uv[c] = ordf(sc[r][c * 64 + lane]);

    // radix select: ksel-th largest
    unsigned prefix = 0, msk = 0;
    int krem = ksel;
    #pragma unroll
    for (int shift = 24; shift >= 0; shift -= 8) {
      { int4 z = {0, 0, 0, 0}; *(int4*)&hist[w][lane * 4] = z; }
      wave_lds_fence();
      #pragma unroll
      for (int c = 0; c < 16; c++) {
        const int j = c * 64 + lane;
        if (j < L && (uv[c] & msk) == prefix)
          atomicAdd(&hist[w][(uv[c] >> shift) & 255], 1);
      }
      wave_lds_fence();
      const int4 cv = *(const int4*)&hist[w][252 - lane * 4];
      int c4[4] = { cv.w, cv.z, cv.y, cv.x };    // descending bins 255-4l..252-4l
      const int lsum = c4[0] + c4[1] + c4[2] + c4[3];
      int x = lsum;
      #pragma unroll
      for (int d2 = 1; d2 < 64; d2 <<= 1) { int y = __shfl_up(x, d2); if (lane >= d2) x += y; }
      int run = x - lsum;
      int fbin = -1, fbefore = 0;
      #pragma unroll
      for (int j2 = 0; j2 < 4; j2++) {
        if (fbin < 0 && run < krem && run + c4[j2] >= krem) { fbin = 255 - lane*4 - j2; fbefore = run; }
        run += c4[j2];
      }
      unsigned long long bal = __ballot(fbin >= 0);
      int bin = 0, before = 0;
      if (bal != 0ull) {                         // wave-uniform branch
        const int srcl = __ffsll((unsigned long long)bal) - 1;
        bin = __shfl(fbin, srcl);
        before = __shfl(fbefore, srcl);
        if (bin < 0) bin = 0;
      }
      krem -= before; if (krem < 1) krem = 1;
      prefix |= ((unsigned)bin) << shift;
      msk |= 0xFFu << shift;
    }
    const unsigned tau = prefix;

    int cg = 0;
    #pragma unroll
    for (int c = 0; c < 16; c++) {
      const int j = c * 64 + lane;
      if (j < L && uv[c] > tau) cg++;
    }
    const int mgt = wave_sum_i(cg);
    const int tie_budget = ksel - mgt;           // >=1 when tau exact

    // keep mask + max over kept (register pass)
    unsigned keep = 0;
    int tiebase = 0;
    float mx = -3.0e38f;
    #pragma unroll
    for (int c = 0; c < 16; c++) {
      const int j = c * 64 + lane;
      const bool act = j < L;
      const unsigned u = uv[c];
      const bool eq = act && (u == tau);
      const unsigned long long bal = __ballot(eq);
      const int trank = tiebase + (int)__popcll(bal & ((1ull << lane) - 1ull));
      tiebase += (int)__popcll(bal);
      const bool kept = act && ((u > tau) || (eq && trank < tie_budget) || (j < MIN_IDX));
      if (kept) { keep |= (1u << c); mx = fmaxf(mx, iordf(u)); }
    }
    mx = wave_max_f(mx);                         // sink j=0 always kept => finite
    float ssum = 0.f;
    #pragma unroll
    for (int c = 0; c < 16; c++) {
      float e = 0.f;
      if ((keep >> c) & 1u) e = __expf(iordf(uv[c]) - mx);
      sc[r][c * 64 + lane] = e;
      ssum += e;
    }
    ssum = wave_sum_f(ssum);
    if (lane == 0) rowinv[r] = 1.f / fmaxf(ssum, 1e-30f);
  }
  __syncthreads();

  // ---- Phase 3: PV (V fragments direct from global) ----
  f32x4 opv[2];
  opv[0] = (f32x4){0.f,0.f,0.f,0.f}; opv[1] = (f32x4){0.f,0.f,0.f,0.f};
  const float inv = rowinv[mcol];
  for (int kt = 0; kt < kt_max; kt++) {
    #pragma unroll
    for (int kb = 0; kb < 4; kb++) {
      const float* prow = &sc[mcol][kt*128 + kb*32 + quad*8];
      float4 p0 = *(const float4*)prow;
      float4 p1 = *(const float4*)(prow + 4);
      union { short8 s; unsigned u[4]; } af;
      af.u[0] = pk2(p0.x * inv, p0.y * inv);
      af.u[1] = pk2(p0.z * inv, p0.w * inv);
      af.u[2] = pk2(p1.x * inv, p1.y * inv);
      af.u[3] = pk2(p1.z * inv, p1.w * inv);
      #pragma unroll
      for (int n2 = 0; n2 < 2; n2++) {
        const int d = (w*2 + n2) * 16 + mcol;
        short8 bfr = *(const short8*)(Vh + (size_t)d * S_LEN + kt*128 + kb*32 + quad*8);
        opv[n2] = __builtin_amdgcn_mfma_f32_16x16x32_bf16(af.s, bfr, opv[n2], 0, 0, 0);
      }
    }
  }
  #pragma unroll
  for (int n2 = 0; n2 < 2; n2++) {
    const int col = h * HD + (w*2 + n2) * 16 + mcol;
    #pragma unroll
    for (int r2 = 0; r2 < 4; r2++) {
      const int row = q0 + quad*4 + r2;
      AO[(size_t)row * AO_COLS + col] = f2bf(opv[n2][r2]);
    }
  }
}

// ---------------------------------------------------------------------------
// Kernel 4: output projection.  out[s][n] = sum_o AO[s][o] * Wo[n][o]
// ---------------------------------------------------------------------------
__global__ __launch_bounds__(256) void gemm_out_k(
    const unsigned short* __restrict__ A, const float* __restrict__ Wo,
    float* __restrict__ Out)
{
  __shared__ unsigned short As[128][40];
  __shared__ unsigned short Bs[128][40];
  const int n0 = blockIdx.x * 128;
  const int m0 = blockIdx.y * 128;
  const float* Bp = Wo + (size_t)n0 * AO_COLS;

  const int t = threadIdx.x;
  const int w = t >> 6, lane = t & 63;
  const int wm = w >> 1, wn = w & 1;
  const int mcol = lane & 15, quad = lane >> 4;
  const int srow = t >> 1;
  const int sseg = (t & 1) * 16;

  f32x4 acc[4][4];
  #pragma unroll
  for (int i = 0; i < 4; i++)
    #pragma unroll
    for (int j = 0; j < 4; j++) acc[i][j] = (f32x4){0.f, 0.f, 0.f, 0.f};

  for (int k0 = 0; k0 < AO_COLS; k0 += 32) {
    const unsigned short* ga = A + (size_t)(m0 + srow) * AO_COLS + k0 + sseg;
    uint4 ua0 = ((const uint4*)ga)[0], ua1 = ((const uint4*)ga)[1];
    const float* gb = Bp + (size_t)srow * AO_COLS + k0 + sseg;
    float4 b0 = ((const float4*)gb)[0], b1 = ((const float4*)gb)[1];
    float4 b2 = ((const float4*)gb)[2], b3 = ((const float4*)gb)[3];
    *(uint4*)&As[srow][sseg]      = ua0;
    *(uint4*)&As[srow][sseg + 8]  = ua1;
    *(short8*)&Bs[srow][sseg]     = pack8(b0, b1);
    *(short8*)&Bs[srow][sseg + 8] = pack8(b2, b3);
    __syncthreads();
    short8 af[4], bf[4];
    #pragma unroll
    for (int i = 0; i < 4; i++) af[i] = *(const short8*)&As[wm*64 + i*16 + mcol][quad*8];
    #pragma unroll
    for (int j = 0; j < 4; j++) bf[j] = *(const short8*)&Bs[wn*64 + j*16 + mcol][quad*8];
    #pragma unroll
    for (int i = 0; i < 4; i++)
      #pragma unroll
      for (int j = 0; j < 4; j++)
        acc[i][j] = __builtin_amdgcn_mfma_f32_16x16x32_bf16(af[i], bf[j], acc[i][j], 0, 0, 0);
    __syncthreads();
  }
  #pragma unroll
  for (int i = 0; i < 4; i++) {
    const int rb = m0 + wm*64 + i*16 + quad*4;
    #pragma unroll
    for (int j = 0; j < 4; j++) {
      const int col = n0 + wn*64 + j*16 + mcol;
      #pragma unroll
      for (int r = 0; r < 4; r++)
        Out[(size_t)(rb + r) * HID + col] = acc[i][j][r];
    }
  }
}

// ---------------------------------------------------------------------------
// Workspace layout (20,971,520 bytes total):
//   [0)          Qraw bf16 [NH][S][HD]          8,388,608
//   [+8388608)   Kraw bf16 [NKV][S][HD]         2,097,152
//   [+10485760)  Vt   bf16 [NKV][HD][S]         2,097,152
//   [+12582912)  AO   bf16 [S][NH*HD]           8,388,608
// ---------------------------------------------------------------------------
extern "C" void kernel_launch(void* const* d_in, const int* in_sizes, int n_in,
                              void* d_out, int out_size, void* d_ws, size_t ws_size,
                              hipStream_t stream) {
  (void)in_sizes; (void)n_in; (void)out_size; (void)ws_size;
  const float* X   = (const float*)d_in[0];
  const int*   pos = (const int*)d_in[1];
  const float* Wq  = (const float*)d_in[2];
  const float* Wk  = (const float*)d_in[3];
  const float* Wv  = (const float*)d_in[4];
  const float* Wo  = (const float*)d_in[5];
  float* out = (float*)d_out;

  char* ws = (char*)d_ws;
  unsigned short* Qraw = (unsigned short*)ws;
  unsigned short* Kraw = (unsigned short*)(ws + 8388608);
  unsigned short* Vt   = (unsigned short*)(ws + 10485760);
  unsigned short* AO   = (unsigned short*)(ws + 12582912);

  gemm_qkv_k<<<dim3(48, 8),  dim3(256), 0, stream>>>(X, Wq, Wk, Wv, Qraw, Kraw, Vt);
  rope_qk_k <<<dim3(10240),  dim3(256), 0, stream>>>(pos, Qraw, Kraw);
  attn_k    <<<dim3(64, 32), dim3(256), 0, stream>>>(Qraw, Kraw, Vt, AO);
  gemm_out_k<<<dim3(32, 8),  dim3(256), 0, stream>>>(AO, Wo, out);
}

// Round 5
// 599.358 us; speedup vs baseline: 1.6799x; 1.2078x over previous
//
#include <hip/hip_runtime.h>
#include <hip/hip_bf16.h>

// Problem constants
#define S_LEN 1024
#define HID   4096
#define NH    32
#define NKV   8
#define HD    128
#define MIN_IDX 4
#define AO_COLS 4096        // NH*HD
#define HEAD_STRIDE 131072  // S_LEN*HD

typedef __attribute__((ext_vector_type(8))) short short8;
typedef __attribute__((ext_vector_type(4))) float f32x4;

__device__ __forceinline__ unsigned short f2bf(float f) {
  union { float f; unsigned u; } v; v.f = f;
  unsigned r = v.u + 0x7FFFu + ((v.u >> 16) & 1u);   // RNE
  return (unsigned short)(r >> 16);
}
__device__ __forceinline__ float bf2f(unsigned short h) {
  union { unsigned u; float f; } v; v.u = ((unsigned)h) << 16;
  return v.f;
}
__device__ __forceinline__ unsigned pk2(float a, float b) {
  union { __hip_bfloat162 h; unsigned u; } c;
  c.h = __float22bfloat162_rn(make_float2(a, b));    // v_cvt_pk_bf16_f32
  return c.u;
}
__device__ __forceinline__ short8 pack8(float4 a, float4 b) {
  union { short8 s; unsigned u[4]; } r;
  r.u[0] = pk2(a.x, a.y); r.u[1] = pk2(a.z, a.w);
  r.u[2] = pk2(b.x, b.y); r.u[3] = pk2(b.z, b.w);
  return r.s;
}
// float -> order-preserving uint, and inverse
__device__ __forceinline__ unsigned ordf(float f) {
  union { float f; int i; } v; v.f = f;
  return (unsigned)(v.i ^ ((v.i >> 31) | 0x80000000));
}
__device__ __forceinline__ float iordf(unsigned u) {
  union { int i; float f; } v;
  v.i = (u & 0x80000000u) ? (int)(u ^ 0x80000000u) : (int)~u;
  return v.f;
}
__device__ __forceinline__ int wave_sum_i(int v) {
  #pragma unroll
  for (int m = 32; m >= 1; m >>= 1) v += __shfl_xor(v, m);
  return v;
}
__device__ __forceinline__ float wave_sum_f(float v) {
  #pragma unroll
  for (int m = 32; m >= 1; m >>= 1) v += __shfl_xor(v, m);
  return v;
}
__device__ __forceinline__ float wave_max_f(float v) {
  #pragma unroll
  for (int m = 32; m >= 1; m >>= 1) v = fmaxf(v, __shfl_xor(v, m));
  return v;
}
// wave-local LDS fence: hist[w] is wave-private, so no block barrier needed.
__device__ __forceinline__ void wave_lds_fence() {
  __builtin_amdgcn_s_waitcnt(0);        // vmcnt(0) expcnt(0) lgkmcnt(0)
  __builtin_amdgcn_wave_barrier();      // stop compiler reordering
}
// async global->LDS, 16 B per lane. LDS dest: wave-uniform base + lane*16.
__device__ __forceinline__ void gload_lds16(const unsigned short* g, unsigned short* l) {
  auto gp = (const __attribute__((address_space(1))) unsigned*)g;
  auto lp = (__attribute__((address_space(3))) unsigned*)(unsigned)(unsigned long long)l;
  __builtin_amdgcn_global_load_lds(gp, lp, 16, 0, 0);
}

// ---------------------------------------------------------------------------
// Kernel 0: fp32 -> bf16 convert (8 elems/thread). n must be multiple of 2048.
// ---------------------------------------------------------------------------
__global__ __launch_bounds__(256) void cvt_k(
    const float* __restrict__ src, unsigned short* __restrict__ dst)
{
  const size_t i = ((size_t)blockIdx.x * 256 + threadIdx.x) * 8;
  float4 a = *(const float4*)(src + i);
  float4 b = *(const float4*)(src + i + 4);
  *(short8*)(dst + i) = pack8(a, b);
}

// ---------------------------------------------------------------------------
// Kernel 1: QKV projection (NT gemm, all-bf16, m97-style global_load_lds).
//   Y[s][n] = sum_k Xb[s][k] * Wb[n][k], Wb = [Wq;Wk;Wv] contiguous [6144][4096]
// Epilogue:
//   Q tiles (nt<32)  -> Qraw[h][s][d]
//   K tiles (32..39) -> Kraw[kvh][s][d]
//   V tiles (40..47) -> Vt[kvh][d][s]   (pre-transposed, ushort4 stores)
// ---------------------------------------------------------------------------
__global__ __launch_bounds__(256) void gemm_qkv_k(
    const unsigned short* __restrict__ Xb, const unsigned short* __restrict__ Wb,
    unsigned short* __restrict__ Qraw, unsigned short* __restrict__ Kraw,
    unsigned short* __restrict__ Vt)
{
  __shared__ unsigned short As[128 * 32];  // unpadded: global_load_lds layout
  __shared__ unsigned short Bs[128 * 32];
  const int nt = blockIdx.x;               // 0..47
  const int n0 = nt * 128;
  const int m0 = blockIdx.y * 128;
  const int t = threadIdx.x, w = t >> 6, lane = t & 63;
  const int wm = w >> 1, wn = w & 1;
  const int mcol = lane & 15, quad = lane >> 4;
  const int lrow = lane >> 2, lcol = (lane & 3) * 8;   // staging map (16B/lane)

  const unsigned short* Ag = Xb + (size_t)m0 * HID;
  const unsigned short* Bg = Wb + (size_t)n0 * HID;

  f32x4 acc[4][4];
  #pragma unroll
  for (int i = 0; i < 4; i++)
    #pragma unroll
    for (int j = 0; j < 4; j++) acc[i][j] = (f32x4){0.f, 0.f, 0.f, 0.f};

  for (int k0 = 0; k0 < HID; k0 += 32) {
    #pragma unroll
    for (int c2 = 0; c2 < 2; c2++) {
      const int c = w * 2 + c2;            // chunk: rows c*16..c*16+15
      gload_lds16(Ag + (size_t)(c*16 + lrow) * HID + k0 + lcol, &As[c * 512]);
      gload_lds16(Bg + (size_t)(c*16 + lrow) * HID + k0 + lcol, &Bs[c * 512]);
    }
    __syncthreads();                       // drains vmcnt -> LDS valid
    short8 af[4], bf[4];
    #pragma unroll
    for (int i = 0; i < 4; i++) af[i] = *(const short8*)&As[(wm*64 + i*16 + mcol)*32 + quad*8];
    #pragma unroll
    for (int j = 0; j < 4; j++) bf[j] = *(const short8*)&Bs[(wn*64 + j*16 + mcol)*32 + quad*8];
    #pragma unroll
    for (int i = 0; i < 4; i++)
      #pragma unroll
      for (int j = 0; j < 4; j++)
        acc[i][j] = __builtin_amdgcn_mfma_f32_16x16x32_bf16(af[i], bf[j], acc[i][j], 0, 0, 0);
    __syncthreads();
  }

  if (nt < 40) {
    unsigned short* dst = (nt < 32) ? (Qraw + (size_t)nt * HEAD_STRIDE)
                                    : (Kraw + (size_t)(nt - 32) * HEAD_STRIDE);
    #pragma unroll
    for (int i = 0; i < 4; i++) {
      const int rb = m0 + wm*64 + i*16 + quad*4;   // C/D: row=(lane>>4)*4+reg
      #pragma unroll
      for (int j = 0; j < 4; j++) {
        const int d = wn*64 + j*16 + mcol;         // col=lane&15
        #pragma unroll
        for (int r = 0; r < 4; r++)
          dst[(size_t)(rb + r) * HD + d] = f2bf(acc[i][j][r]);
      }
    }
  } else {
    unsigned short* dst = Vt + (size_t)(nt - 40) * HEAD_STRIDE;
    #pragma unroll
    for (int i = 0; i < 4; i++) {
      const int rb = m0 + wm*64 + i*16 + quad*4;   // 4 consecutive s per lane
      #pragma unroll
      for (int j = 0; j < 4; j++) {
        const int d = wn*64 + j*16 + mcol;
        ushort4 v4;
        v4.x = f2bf(acc[i][j][0]); v4.y = f2bf(acc[i][j][1]);
        v4.z = f2bf(acc[i][j][2]); v4.w = f2bf(acc[i][j][3]);
        *(ushort4*)(dst + (size_t)d * S_LEN + rb) = v4;
      }
    }
  }
}

// ---------------------------------------------------------------------------
// Kernel 2: RoPE in-place on bf16 Q and K. One wave per (head_row, s).
// ---------------------------------------------------------------------------
__global__ __launch_bounds__(256) void rope_qk_k(
    const int* __restrict__ pos_ids,
    unsigned short* __restrict__ Qraw, unsigned short* __restrict__ Kraw)
{
  const int w = threadIdx.x >> 6, lane = threadIdx.x & 63;
  const int gw = blockIdx.x * 4 + w;           // 0 .. (NH+NKV)*S-1
  const int hidx = gw >> 10;
  const int s = gw & 1023;
  const float pos = (float)pos_ids[s];
  const float invf = powf(10000.0f, -(float)lane * (1.0f / 64.0f));
  float sn, cs;
  sincosf(pos * invf, &sn, &cs);
  unsigned short* base = (hidx < NH)
      ? (Qraw + (size_t)hidx * HEAD_STRIDE + (size_t)s * HD)
      : (Kraw + (size_t)(hidx - NH) * HEAD_STRIDE + (size_t)s * HD);
  const float x0 = bf2f(base[lane]), x1 = bf2f(base[lane + 64]);
  base[lane]      = f2bf(x0 * cs - x1 * sn);
  base[lane + 64] = f2bf(x1 * cs + x0 * sn);
}

// ---------------------------------------------------------------------------
// Kernel 3: fused sparse attention (unchanged from round 4).
// ---------------------------------------------------------------------------
#define SCS 1028
__global__ __launch_bounds__(256) void attn_k(
    const unsigned short* __restrict__ Qb, const unsigned short* __restrict__ Kb,
    const unsigned short* __restrict__ Vt, unsigned short* __restrict__ AO)
{
  __shared__ float sc[16][SCS];                // 65792 B
  __shared__ int hist[4][256];                 // wave-private rows
  __shared__ float rowinv[16];
  const int rb = (int)gridDim.x - 1 - (int)blockIdx.x;  // heavy blocks first
  const int h = blockIdx.y;
  const int kvh = h >> 2;                      // GROUPS=4
  const int q0 = rb * 16;
  const int kt_max = (q0 + 16 + 127) >> 7;
  const int t = threadIdx.x, w = t >> 6, lane = t & 63;
  const int mcol = lane & 15, quad = lane >> 4;
  const float scale = 0.08838834764831845f;    // 1/sqrt(128)

  const unsigned short* Kh = Kb + (size_t)kvh * HEAD_STRIDE;  // [s][d]
  const unsigned short* Vh = Vt + (size_t)kvh * HEAD_STRIDE;  // [d][s]

  short8 aq[4];
  {
    const unsigned short* qrow = Qb + ((size_t)h * S_LEN + q0 + mcol) * HD + quad * 8;
    #pragma unroll
    for (int kk = 0; kk < 4; kk++) aq[kk] = *(const short8*)(qrow + kk * 32);
  }

  // ---- Phase 1: scores (K fragments direct from global) ----
  for (int kt = 0; kt < kt_max; kt++) {
    #pragma unroll
    for (int g2 = 0; g2 < 2; g2++) {
      const int g = w * 2 + g2;
      const int key = kt * 128 + g * 16 + mcol;
      const unsigned short* krow = Kh + (size_t)key * HD + quad * 8;
      f32x4 d4 = {0.f, 0.f, 0.f, 0.f};
      #pragma unroll
      for (int kk = 0; kk < 4; kk++) {
        short8 bfr = *(const short8*)(krow + kk * 32);
        d4 = __builtin_amdgcn_mfma_f32_16x16x32_bf16(aq[kk], bfr, d4, 0, 0, 0);
      }
      const int col = kt * 128 + g * 16 + mcol;
      #pragma unroll
      for (int r = 0; r < 4; r++) sc[quad*4 + r][col] = d4[r] * scale;
    }
  }
  __syncthreads();

  // ---- Phase 2: selection + softmax (wave w owns rows w*4 .. w*4+3) ----
  for (int i = 0; i < 4; i++) {
    const int r = w * 4 + i;
    const int q = q0 + r;
    const int L = q + 1;
    int ksel = L >> 1; if (ksel < 1) ksel = 1;

    unsigned uv[16];
    #pragma unroll
    for (int c = 0; c < 16; c++) uv[c] = ordf(sc[r][c * 64 + lane]);

    unsigned prefix = 0, msk = 0;
    int krem = ksel;
    #pragma unroll
    for (int shift = 24; shift >= 0; shift -= 8) {
      { int4 z = {0, 0, 0, 0}; *(int4*)&hist[w][lane * 4] = z; }
      wave_lds_fence();
      #pragma unroll
      for (int c = 0; c < 16; c++) {
        const int j = c * 64 + lane;
        if (j < L && (uv[c] & msk) == prefix)
          atomicAdd(&hist[w][(uv[c] >> shift) & 255], 1);
      }
      wave_lds_fence();
      const int4 cv = *(const int4*)&hist[w][252 - lane * 4];
      int c4[4] = { cv.w, cv.z, cv.y, cv.x };    // descending bins
      const int lsum = c4[0] + c4[1] + c4[2] + c4[3];
      int x = lsum;
      #pragma unroll
      for (int d2 = 1; d2 < 64; d2 <<= 1) { int y = __shfl_up(x, d2); if (lane >= d2) x += y; }
      int run = x - lsum;
      int fbin = -1, fbefore = 0;
      #pragma unroll
      for (int j2 = 0; j2 < 4; j2++) {
        if (fbin < 0 && run < krem && run + c4[j2] >= krem) { fbin = 255 - lane*4 - j2; fbefore = run; }
        run += c4[j2];
      }
      unsigned long long bal = __ballot(fbin >= 0);
      int bin = 0, before = 0;
      if (bal != 0ull) {
        const int srcl = __ffsll((unsigned long long)bal) - 1;
        bin = __shfl(fbin, srcl);
        before = __shfl(fbefore, srcl);
        if (bin < 0) bin = 0;
      }
      krem -= before; if (krem < 1) krem = 1;
      prefix |= ((unsigned)bin) << shift;
      msk |= 0xFFu << shift;
    }
    const unsigned tau = prefix;

    int cg = 0;
    #pragma unroll
    for (int c = 0; c < 16; c++) {
      const int j = c * 64 + lane;
      if (j < L && uv[c] > tau) cg++;
    }
    const int mgt = wave_sum_i(cg);
    const int tie_budget = ksel - mgt;

    unsigned keep = 0;
    int tiebase = 0;
    float mx = -3.0e38f;
    #pragma unroll
    for (int c = 0; c < 16; c++) {
      const int j = c * 64 + lane;
      const bool act = j < L;
      const unsigned u = uv[c];
      const bool eq = act && (u == tau);
      const unsigned long long bal = __ballot(eq);
      const int trank = tiebase + (int)__popcll(bal & ((1ull << lane) - 1ull));
      tiebase += (int)__popcll(bal);
      const bool kept = act && ((u > tau) || (eq && trank < tie_budget) || (j < MIN_IDX));
      if (kept) { keep |= (1u << c); mx = fmaxf(mx, iordf(u)); }
    }
    mx = wave_max_f(mx);
    float ssum = 0.f;
    #pragma unroll
    for (int c = 0; c < 16; c++) {
      float e = 0.f;
      if ((keep >> c) & 1u) e = __expf(iordf(uv[c]) - mx);
      sc[r][c * 64 + lane] = e;
      ssum += e;
    }
    ssum = wave_sum_f(ssum);
    if (lane == 0) rowinv[r] = 1.f / fmaxf(ssum, 1e-30f);
  }
  __syncthreads();

  // ---- Phase 3: PV (V fragments direct from global) ----
  f32x4 opv[2];
  opv[0] = (f32x4){0.f,0.f,0.f,0.f}; opv[1] = (f32x4){0.f,0.f,0.f,0.f};
  const float inv = rowinv[mcol];
  for (int kt = 0; kt < kt_max; kt++) {
    #pragma unroll
    for (int kb = 0; kb < 4; kb++) {
      const float* prow = &sc[mcol][kt*128 + kb*32 + quad*8];
      float4 p0 = *(const float4*)prow;
      float4 p1 = *(const float4*)(prow + 4);
      union { short8 s; unsigned u[4]; } af;
      af.u[0] = pk2(p0.x * inv, p0.y * inv);
      af.u[1] = pk2(p0.z * inv, p0.w * inv);
      af.u[2] = pk2(p1.x * inv, p1.y * inv);
      af.u[3] = pk2(p1.z * inv, p1.w * inv);
      #pragma unroll
      for (int n2 = 0; n2 < 2; n2++) {
        const int d = (w*2 + n2) * 16 + mcol;
        short8 bfr = *(const short8*)(Vh + (size_t)d * S_LEN + kt*128 + kb*32 + quad*8);
        opv[n2] = __builtin_amdgcn_mfma_f32_16x16x32_bf16(af.s, bfr, opv[n2], 0, 0, 0);
      }
    }
  }
  #pragma unroll
  for (int n2 = 0; n2 < 2; n2++) {
    const int col = h * HD + (w*2 + n2) * 16 + mcol;
    #pragma unroll
    for (int r2 = 0; r2 < 4; r2++) {
      const int row = q0 + quad*4 + r2;
      AO[(size_t)row * AO_COLS + col] = f2bf(opv[n2][r2]);
    }
  }
}

// ---------------------------------------------------------------------------
// Kernel 4: output projection (all-bf16, m97-style global_load_lds).
//   out[s][n] = sum_o AO[s][o] * Wob[n][o]
// ---------------------------------------------------------------------------
__global__ __launch_bounds__(256) void gemm_out_k(
    const unsigned short* __restrict__ A, const unsigned short* __restrict__ Wob,
    float* __restrict__ Out)
{
  __shared__ unsigned short As[128 * 32];
  __shared__ unsigned short Bs[128 * 32];
  const int n0 = blockIdx.x * 128;
  const int m0 = blockIdx.y * 128;
  const int t = threadIdx.x, w = t >> 6, lane = t & 63;
  const int wm = w >> 1, wn = w & 1;
  const int mcol = lane & 15, quad = lane >> 4;
  const int lrow = lane >> 2, lcol = (lane & 3) * 8;

  const unsigned short* Ag = A   + (size_t)m0 * AO_COLS;
  const unsigned short* Bg = Wob + (size_t)n0 * AO_COLS;

  f32x4 acc[4][4];
  #pragma unroll
  for (int i = 0; i < 4; i++)
    #pragma unroll
    for (int j = 0; j < 4; j++) acc[i][j] = (f32x4){0.f, 0.f, 0.f, 0.f};

  for (int k0 = 0; k0 < AO_COLS; k0 += 32) {
    #pragma unroll
    for (int c2 = 0; c2 < 2; c2++) {
      const int c = w * 2 + c2;
      gload_lds16(Ag + (size_t)(c*16 + lrow) * AO_COLS + k0 + lcol, &As[c * 512]);
      gload_lds16(Bg + (size_t)(c*16 + lrow) * AO_COLS + k0 + lcol, &Bs[c * 512]);
    }
    __syncthreads();
    short8 af[4], bf[4];
    #pragma unroll
    for (int i = 0; i < 4; i++) af[i] = *(const short8*)&As[(wm*64 + i*16 + mcol)*32 + quad*8];
    #pragma unroll
    for (int j = 0; j < 4; j++) bf[j] = *(const short8*)&Bs[(wn*64 + j*16 + mcol)*32 + quad*8];
    #pragma unroll
    for (int i = 0; i < 4; i++)
      #pragma unroll
      for (int j = 0; j < 4; j++)
        acc[i][j] = __builtin_amdgcn_mfma_f32_16x16x32_bf16(af[i], bf[j], acc[i][j], 0, 0, 0);
    __syncthreads();
  }
  #pragma unroll
  for (int i = 0; i < 4; i++) {
    const int rb = m0 + wm*64 + i*16 + quad*4;
    #pragma unroll
    for (int j = 0; j < 4; j++) {
      const int col = n0 + wn*64 + j*16 + mcol;
      #pragma unroll
      for (int r = 0; r < 4; r++)
        Out[(size_t)(rb + r) * HID + col] = acc[i][j][r];
    }
  }
}

// ---------------------------------------------------------------------------
// Workspace layout (79,691,776 bytes total):
//   [0)          Qraw  bf16 [NH][S][HD]          8,388,608
//   [+8388608)   Kraw  bf16 [NKV][S][HD]         2,097,152
//   [+10485760)  Vt    bf16 [NKV][HD][S]         2,097,152
//   [+12582912)  AO    bf16 [S][NH*HD]           8,388,608
//   [+20971520)  Xb    bf16 [S][HID]             8,388,608
//   [+29360128)  Wqkvb bf16 [6144][4096]        50,331,648
//                Wob   bf16 [4096][4096] aliases Wqkvb (cvt after gemm_qkv)
// ---------------------------------------------------------------------------
extern "C" void kernel_launch(void* const* d_in, const int* in_sizes, int n_in,
                              void* d_out, int out_size, void* d_ws, size_t ws_size,
                              hipStream_t stream) {
  (void)in_sizes; (void)n_in; (void)out_size; (void)ws_size;
  const float* X   = (const float*)d_in[0];
  const int*   pos = (const int*)d_in[1];
  const float* Wq  = (const float*)d_in[2];
  const float* Wk  = (const float*)d_in[3];
  const float* Wv  = (const float*)d_in[4];
  const float* Wo  = (const float*)d_in[5];
  float* out = (float*)d_out;

  char* ws = (char*)d_ws;
  unsigned short* Qraw  = (unsigned short*)ws;
  unsigned short* Kraw  = (unsigned short*)(ws + 8388608);
  unsigned short* Vt    = (unsigned short*)(ws + 10485760);
  unsigned short* AO    = (unsigned short*)(ws + 12582912);
  unsigned short* Xb    = (unsigned short*)(ws + 20971520);
  unsigned short* Wqkvb = (unsigned short*)(ws + 29360128);
  unsigned short* Wob   = Wqkvb;   // alias: Wo converted after gemm_qkv reads Wqkvb

  // bf16 conversions (memory-bound; 8 elems/thread)
  cvt_k<<<dim3(2048), dim3(256), 0, stream>>>(X,  Xb);                       // 4.19M
  cvt_k<<<dim3(8192), dim3(256), 0, stream>>>(Wq, Wqkvb);                    // 16.8M
  cvt_k<<<dim3(2048), dim3(256), 0, stream>>>(Wk, Wqkvb + 16777216);         // 4.19M
  cvt_k<<<dim3(2048), dim3(256), 0, stream>>>(Wv, Wqkvb + 20971520);         // 4.19M

  gemm_qkv_k<<<dim3(48, 8),  dim3(256), 0, stream>>>(Xb, Wqkvb, Qraw, Kraw, Vt);
  rope_qk_k <<<dim3(10240),  dim3(256), 0, stream>>>(pos, Qraw, Kraw);

  cvt_k<<<dim3(8192), dim3(256), 0, stream>>>(Wo, Wob);                      // 16.8M

  attn_k    <<<dim3(64, 32), dim3(256), 0, stream>>>(Qraw, Kraw, Vt, AO);
  gemm_out_k<<<dim3(32, 8),  dim3(256), 0, stream>>>(AO, Wob, out);
}

// Round 6
// 581.327 us; speedup vs baseline: 1.7320x; 1.0310x over previous
//
#include <hip/hip_runtime.h>
#include <hip/hip_bf16.h>

// Problem constants
#define S_LEN 1024
#define HID   4096
#define NH    32
#define NKV   8
#define HD    128
#define MIN_IDX 4
#define AO_COLS 4096        // NH*HD
#define HEAD_STRIDE 131072  // S_LEN*HD

typedef __attribute__((ext_vector_type(8))) short short8;
typedef __attribute__((ext_vector_type(4))) float f32x4;

__device__ __forceinline__ unsigned short f2bf(float f) {
  union { float f; unsigned u; } v; v.f = f;
  unsigned r = v.u + 0x7FFFu + ((v.u >> 16) & 1u);   // RNE
  return (unsigned short)(r >> 16);
}
__device__ __forceinline__ float bf2f(unsigned short h) {
  union { unsigned u; float f; } v; v.u = ((unsigned)h) << 16;
  return v.f;
}
__device__ __forceinline__ unsigned pk2(float a, float b) {
  union { __hip_bfloat162 h; unsigned u; } c;
  c.h = __float22bfloat162_rn(make_float2(a, b));    // v_cvt_pk_bf16_f32
  return c.u;
}
__device__ __forceinline__ short8 pack8(float4 a, float4 b) {
  union { short8 s; unsigned u[4]; } r;
  r.u[0] = pk2(a.x, a.y); r.u[1] = pk2(a.z, a.w);
  r.u[2] = pk2(b.x, b.y); r.u[3] = pk2(b.z, b.w);
  return r.s;
}
// float -> order-preserving uint, and inverse
__device__ __forceinline__ unsigned ordf(float f) {
  union { float f; int i; } v; v.f = f;
  return (unsigned)(v.i ^ ((v.i >> 31) | 0x80000000));
}
__device__ __forceinline__ float iordf(unsigned u) {
  union { int i; float f; } v;
  v.i = (u & 0x80000000u) ? (int)(u ^ 0x80000000u) : (int)~u;
  return v.f;
}
__device__ __forceinline__ float u2f_bits(unsigned u) {
  union { unsigned u; float f; } v; v.u = u; return v.f;
}
__device__ __forceinline__ unsigned f2u_bits(float f) {
  union { float f; unsigned u; } v; v.f = f; return v.u;
}
__device__ __forceinline__ int wave_sum_i(int v) {
  #pragma unroll
  for (int m = 32; m >= 1; m >>= 1) v += __shfl_xor(v, m);
  return v;
}
__device__ __forceinline__ float wave_sum_f(float v) {
  #pragma unroll
  for (int m = 32; m >= 1; m >>= 1) v += __shfl_xor(v, m);
  return v;
}
__device__ __forceinline__ float wave_max_f(float v) {
  #pragma unroll
  for (int m = 32; m >= 1; m >>= 1) v = fmaxf(v, __shfl_xor(v, m));
  return v;
}
// wave-local LDS fence: hist[w] is wave-private, so no block barrier needed.
__device__ __forceinline__ void wave_lds_fence() {
  __builtin_amdgcn_s_waitcnt(0);        // vmcnt(0) expcnt(0) lgkmcnt(0)
  __builtin_amdgcn_wave_barrier();      // stop compiler reordering
}
// async global->LDS, 16 B per lane. LDS dest: wave-uniform base + lane*16.
__device__ __forceinline__ void gload_lds16(const unsigned short* g, unsigned short* l) {
  auto gp = (const __attribute__((address_space(1))) unsigned*)g;
  auto lp = (__attribute__((address_space(3))) unsigned*)(unsigned)(unsigned long long)l;
  __builtin_amdgcn_global_load_lds(gp, lp, 16, 0, 0);
}

// ---------------------------------------------------------------------------
// Kernel 0: fp32 -> bf16 convert (8 elems/thread). n must be multiple of 2048.
// ---------------------------------------------------------------------------
__global__ __launch_bounds__(256) void cvt_k(
    const float* __restrict__ src, unsigned short* __restrict__ dst)
{
  const size_t i = ((size_t)blockIdx.x * 256 + threadIdx.x) * 8;
  float4 a = *(const float4*)(src + i);
  float4 b = *(const float4*)(src + i + 4);
  *(short8*)(dst + i) = pack8(a, b);
}

// ---------------------------------------------------------------------------
// Kernel 1: QKV projection (NT gemm, all-bf16, m97-style global_load_lds).
// ---------------------------------------------------------------------------
__global__ __launch_bounds__(256) void gemm_qkv_k(
    const unsigned short* __restrict__ Xb, const unsigned short* __restrict__ Wb,
    unsigned short* __restrict__ Qraw, unsigned short* __restrict__ Kraw,
    unsigned short* __restrict__ Vt)
{
  __shared__ unsigned short As[128 * 32];  // unpadded: global_load_lds layout
  __shared__ unsigned short Bs[128 * 32];
  const int nt = blockIdx.x;               // 0..47
  const int n0 = nt * 128;
  const int m0 = blockIdx.y * 128;
  const int t = threadIdx.x, w = t >> 6, lane = t & 63;
  const int wm = w >> 1, wn = w & 1;
  const int mcol = lane & 15, quad = lane >> 4;
  const int lrow = lane >> 2, lcol = (lane & 3) * 8;   // staging map (16B/lane)

  const unsigned short* Ag = Xb + (size_t)m0 * HID;
  const unsigned short* Bg = Wb + (size_t)n0 * HID;

  f32x4 acc[4][4];
  #pragma unroll
  for (int i = 0; i < 4; i++)
    #pragma unroll
    for (int j = 0; j < 4; j++) acc[i][j] = (f32x4){0.f, 0.f, 0.f, 0.f};

  for (int k0 = 0; k0 < HID; k0 += 32) {
    #pragma unroll
    for (int c2 = 0; c2 < 2; c2++) {
      const int c = w * 2 + c2;            // chunk: rows c*16..c*16+15
      gload_lds16(Ag + (size_t)(c*16 + lrow) * HID + k0 + lcol, &As[c * 512]);
      gload_lds16(Bg + (size_t)(c*16 + lrow) * HID + k0 + lcol, &Bs[c * 512]);
    }
    __syncthreads();                       // drains vmcnt -> LDS valid
    short8 af[4], bf[4];
    #pragma unroll
    for (int i = 0; i < 4; i++) af[i] = *(const short8*)&As[(wm*64 + i*16 + mcol)*32 + quad*8];
    #pragma unroll
    for (int j = 0; j < 4; j++) bf[j] = *(const short8*)&Bs[(wn*64 + j*16 + mcol)*32 + quad*8];
    #pragma unroll
    for (int i = 0; i < 4; i++)
      #pragma unroll
      for (int j = 0; j < 4; j++)
        acc[i][j] = __builtin_amdgcn_mfma_f32_16x16x32_bf16(af[i], bf[j], acc[i][j], 0, 0, 0);
    __syncthreads();
  }

  if (nt < 40) {
    unsigned short* dst = (nt < 32) ? (Qraw + (size_t)nt * HEAD_STRIDE)
                                    : (Kraw + (size_t)(nt - 32) * HEAD_STRIDE);
    #pragma unroll
    for (int i = 0; i < 4; i++) {
      const int rb = m0 + wm*64 + i*16 + quad*4;   // C/D: row=(lane>>4)*4+reg
      #pragma unroll
      for (int j = 0; j < 4; j++) {
        const int d = wn*64 + j*16 + mcol;         // col=lane&15
        #pragma unroll
        for (int r = 0; r < 4; r++)
          dst[(size_t)(rb + r) * HD + d] = f2bf(acc[i][j][r]);
      }
    }
  } else {
    unsigned short* dst = Vt + (size_t)(nt - 40) * HEAD_STRIDE;
    #pragma unroll
    for (int i = 0; i < 4; i++) {
      const int rb = m0 + wm*64 + i*16 + quad*4;   // 4 consecutive s per lane
      #pragma unroll
      for (int j = 0; j < 4; j++) {
        const int d = wn*64 + j*16 + mcol;
        ushort4 v4;
        v4.x = f2bf(acc[i][j][0]); v4.y = f2bf(acc[i][j][1]);
        v4.z = f2bf(acc[i][j][2]); v4.w = f2bf(acc[i][j][3]);
        *(ushort4*)(dst + (size_t)d * S_LEN + rb) = v4;
      }
    }
  }
}

// ---------------------------------------------------------------------------
// Kernel 2: RoPE in-place on bf16 Q and K. One wave per (head_row, s).
// ---------------------------------------------------------------------------
__global__ __launch_bounds__(256) void rope_qk_k(
    const int* __restrict__ pos_ids,
    unsigned short* __restrict__ Qraw, unsigned short* __restrict__ Kraw)
{
  const int w = threadIdx.x >> 6, lane = threadIdx.x & 63;
  const int gw = blockIdx.x * 4 + w;           // 0 .. (NH+NKV)*S-1
  const int hidx = gw >> 10;
  const int s = gw & 1023;
  const float pos = (float)pos_ids[s];
  const float invf = powf(10000.0f, -(float)lane * (1.0f / 64.0f));
  float sn, cs;
  sincosf(pos * invf, &sn, &cs);
  unsigned short* base = (hidx < NH)
      ? (Qraw + (size_t)hidx * HEAD_STRIDE + (size_t)s * HD)
      : (Kraw + (size_t)(hidx - NH) * HEAD_STRIDE + (size_t)s * HD);
  const float x0 = bf2f(base[lane]), x1 = bf2f(base[lane + 64]);
  base[lane]      = f2bf(x0 * cs - x1 * sn);
  base[lane + 64] = f2bf(x1 * cs + x0 * sn);
}

// ---------------------------------------------------------------------------
// Kernel 3: fused sparse attention, register-resident scores.
//  Phase 1: per-kt scores -> small LDS chunk scb[16][130] -> captured into
//           per-wave registers su[4][16] (wave w owns rows 4w..4w+3).
//  Phase 2: radix-select + ties + softmax entirely in registers; writes
//           pre-normalized bf16 P into Pl[16][1040] (aliases scb region;
//           safe: phase-1 final barrier separates).
//  Phase 3: PV MFMA reading bf16 A-fragments from Pl, V direct from global.
//  LDS ~37.4 KB -> 3 blocks/CU (launch_bounds 256,3).
// ---------------------------------------------------------------------------
#define PSTR 1040
__global__ __launch_bounds__(256, 3) void attn_k(
    const unsigned short* __restrict__ Qb, const unsigned short* __restrict__ Kb,
    const unsigned short* __restrict__ Vt, unsigned short* __restrict__ AO)
{
  __shared__ unsigned short Pl[16][PSTR];      // 33280 B (bf16 P, pre-normalized)
  __shared__ int hist[4][256];                 // 4096 B (wave-private rows)
  float (*scb)[130] = (float (*)[130])&Pl[0][0];  // 8320 B overlay (phase 1 only)

  const int rb = (int)gridDim.x - 1 - (int)blockIdx.x;  // heavy blocks first
  const int h = blockIdx.y;
  const int kvh = h >> 2;                      // GROUPS=4
  const int q0 = rb * 16;
  const int kt_max = (q0 + 16 + 127) >> 7;     // 1..8
  const int t = threadIdx.x, w = t >> 6, lane = t & 63;
  const int mcol = lane & 15, quad = lane >> 4;
  const float scale = 0.08838834764831845f;    // 1/sqrt(128)

  const unsigned short* Kh = Kb + (size_t)kvh * HEAD_STRIDE;  // [s][d]
  const unsigned short* Vh = Vt + (size_t)kvh * HEAD_STRIDE;  // [d][s]

  short8 aq[4];
  {
    const unsigned short* qrow = Qb + ((size_t)h * S_LEN + q0 + mcol) * HD + quad * 8;
    #pragma unroll
    for (int kk = 0; kk < 4; kk++) aq[kk] = *(const short8*)(qrow + kk * 32);
  }

  // per-wave register copy of the 4 owned rows (ordf-encoded scores)
  unsigned su[4][16];

  // ---- Phase 1: scores -> chunk transpose -> registers ----
  #pragma unroll
  for (int kt = 0; kt < 8; kt++) {
    if (kt >= kt_max) break;                   // kt_max is block-uniform
    // issue all 8 K-fragment loads first (ILP), then MFMA
    short8 bfr[2][4];
    #pragma unroll
    for (int g2 = 0; g2 < 2; g2++) {
      const int key = kt * 128 + (w * 2 + g2) * 16 + mcol;
      const unsigned short* krow = Kh + (size_t)key * HD + quad * 8;
      #pragma unroll
      for (int kk = 0; kk < 4; kk++) bfr[g2][kk] = *(const short8*)(krow + kk * 32);
    }
    f32x4 d4[2];
    d4[0] = (f32x4){0.f,0.f,0.f,0.f}; d4[1] = (f32x4){0.f,0.f,0.f,0.f};
    #pragma unroll
    for (int g2 = 0; g2 < 2; g2++)
      #pragma unroll
      for (int kk = 0; kk < 4; kk++)
        d4[g2] = __builtin_amdgcn_mfma_f32_16x16x32_bf16(aq[kk], bfr[g2][kk], d4[g2], 0, 0, 0);
    #pragma unroll
    for (int g2 = 0; g2 < 2; g2++) {
      const int colc = (w * 2 + g2) * 16 + mcol;
      #pragma unroll
      for (int r = 0; r < 4; r++) scb[quad*4 + r][colc] = d4[g2][r] * scale;
    }
    __syncthreads();
    #pragma unroll
    for (int i = 0; i < 4; i++)
      #pragma unroll
      for (int sub = 0; sub < 2; sub++)
        su[i][kt*2 + sub] = ordf(scb[w*4 + i][sub*64 + lane]);
    __syncthreads();
  }

  // ---- Phase 2: selection + softmax in registers; write bf16 P ----
  const int c_lim = kt_max * 2;                // valid chunks
  #pragma unroll
  for (int i = 0; i < 4; i++) {
    const int r = w * 4 + i;
    const int q = q0 + r;
    const int L = q + 1;
    int ksel = L >> 1; if (ksel < 1) ksel = 1;

    unsigned prefix = 0, msk = 0;
    int krem = ksel;
    #pragma unroll
    for (int shift = 24; shift >= 0; shift -= 8) {
      { int4 z = {0, 0, 0, 0}; *(int4*)&hist[w][lane * 4] = z; }
      wave_lds_fence();
      #pragma unroll
      for (int c = 0; c < 16; c++) {
        const int j = c * 64 + lane;
        if (j < L && (su[i][c] & msk) == prefix)
          atomicAdd(&hist[w][(su[i][c] >> shift) & 255], 1);
      }
      wave_lds_fence();
      const int4 cv = *(const int4*)&hist[w][252 - lane * 4];
      int c4[4] = { cv.w, cv.z, cv.y, cv.x };    // descending bins
      const int lsum = c4[0] + c4[1] + c4[2] + c4[3];
      int x = lsum;
      #pragma unroll
      for (int d2 = 1; d2 < 64; d2 <<= 1) { int y = __shfl_up(x, d2); if (lane >= d2) x += y; }
      int run = x - lsum;
      int fbin = -1, fbefore = 0;
      #pragma unroll
      for (int j2 = 0; j2 < 4; j2++) {
        if (fbin < 0 && run < krem && run + c4[j2] >= krem) { fbin = 255 - lane*4 - j2; fbefore = run; }
        run += c4[j2];
      }
      unsigned long long bal = __ballot(fbin >= 0);
      int bin = 0, before = 0;
      if (bal != 0ull) {
        const int srcl = __ffsll((unsigned long long)bal) - 1;
        bin = __shfl(fbin, srcl);
        before = __shfl(fbefore, srcl);
        if (bin < 0) bin = 0;
      }
      krem -= before; if (krem < 1) krem = 1;
      prefix |= ((unsigned)bin) << shift;
      msk |= 0xFFu << shift;
    }
    const unsigned tau = prefix;

    int cg = 0;
    #pragma unroll
    for (int c = 0; c < 16; c++) {
      const int j = c * 64 + lane;
      if (j < L && su[i][c] > tau) cg++;
    }
    const int mgt = wave_sum_i(cg);
    const int tie_budget = ksel - mgt;

    unsigned keep = 0;
    int tiebase = 0;
    float mx = -3.0e38f;
    #pragma unroll
    for (int c = 0; c < 16; c++) {
      const int j = c * 64 + lane;
      const bool act = j < L;
      const unsigned u = su[i][c];
      const bool eq = act && (u == tau);
      const unsigned long long bal = __ballot(eq);
      const int trank = tiebase + (int)__popcll(bal & ((1ull << lane) - 1ull));
      tiebase += (int)__popcll(bal);
      const bool kept = act && ((u > tau) || (eq && trank < tie_budget) || (j < MIN_IDX));
      if (kept) { keep |= (1u << c); mx = fmaxf(mx, iordf(u)); }
    }
    mx = wave_max_f(mx);                       // sink j=0 always kept => finite
    float ssum = 0.f;
    #pragma unroll
    for (int c = 0; c < 16; c++) {
      float e = 0.f;
      if ((keep >> c) & 1u) e = __expf(iordf(su[i][c]) - mx);
      su[i][c] = f2u_bits(e);                  // stash exp value
      ssum += e;
    }
    ssum = wave_sum_f(ssum);
    const float inv = 1.f / fmaxf(ssum, 1e-30f);
    for (int c = 0; c < c_lim; c++) {          // write pre-normalized bf16 P
      unsigned e;
      switch (c) {                             // constant-index reg access
        case 0: e = su[i][0]; break;   case 1: e = su[i][1]; break;
        case 2: e = su[i][2]; break;   case 3: e = su[i][3]; break;
        case 4: e = su[i][4]; break;   case 5: e = su[i][5]; break;
        case 6: e = su[i][6]; break;   case 7: e = su[i][7]; break;
        case 8: e = su[i][8]; break;   case 9: e = su[i][9]; break;
        case 10: e = su[i][10]; break; case 11: e = su[i][11]; break;
        case 12: e = su[i][12]; break; case 13: e = su[i][13]; break;
        case 14: e = su[i][14]; break; default: e = su[i][15]; break;
      }
      Pl[r][c*64 + lane] = f2bf(u2f_bits(e) * inv);
    }
  }
  __syncthreads();

  // ---- Phase 3: PV (bf16 A from Pl, V direct from global) ----
  f32x4 opv[2];
  opv[0] = (f32x4){0.f,0.f,0.f,0.f}; opv[1] = (f32x4){0.f,0.f,0.f,0.f};
  for (int kt = 0; kt < kt_max; kt++) {
    #pragma unroll
    for (int kb = 0; kb < 4; kb++) {
      short8 af = *(const short8*)&Pl[mcol][kt*128 + kb*32 + quad*8];
      #pragma unroll
      for (int n2 = 0; n2 < 2; n2++) {
        const int d = (w*2 + n2) * 16 + mcol;
        short8 bfr = *(const short8*)(Vh + (size_t)d * S_LEN + kt*128 + kb*32 + quad*8);
        opv[n2] = __builtin_amdgcn_mfma_f32_16x16x32_bf16(af, bfr, opv[n2], 0, 0, 0);
      }
    }
  }
  #pragma unroll
  for (int n2 = 0; n2 < 2; n2++) {
    const int col = h * HD + (w*2 + n2) * 16 + mcol;
    #pragma unroll
    for (int r2 = 0; r2 < 4; r2++) {
      const int row = q0 + quad*4 + r2;
      AO[(size_t)row * AO_COLS + col] = f2bf(opv[n2][r2]);
    }
  }
}

// ---------------------------------------------------------------------------
// Kernel 4: output projection (all-bf16, m97-style global_load_lds).
// ---------------------------------------------------------------------------
__global__ __launch_bounds__(256) void gemm_out_k(
    const unsigned short* __restrict__ A, const unsigned short* __restrict__ Wob,
    float* __restrict__ Out)
{
  __shared__ unsigned short As[128 * 32];
  __shared__ unsigned short Bs[128 * 32];
  const int n0 = blockIdx.x * 128;
  const int m0 = blockIdx.y * 128;
  const int t = threadIdx.x, w = t >> 6, lane = t & 63;
  const int wm = w >> 1, wn = w & 1;
  const int mcol = lane & 15, quad = lane >> 4;
  const int lrow = lane >> 2, lcol = (lane & 3) * 8;

  const unsigned short* Ag = A   + (size_t)m0 * AO_COLS;
  const unsigned short* Bg = Wob + (size_t)n0 * AO_COLS;

  f32x4 acc[4][4];
  #pragma unroll
  for (int i = 0; i < 4; i++)
    #pragma unroll
    for (int j = 0; j < 4; j++) acc[i][j] = (f32x4){0.f, 0.f, 0.f, 0.f};

  for (int k0 = 0; k0 < AO_COLS; k0 += 32) {
    #pragma unroll
    for (int c2 = 0; c2 < 2; c2++) {
      const int c = w * 2 + c2;
      gload_lds16(Ag + (size_t)(c*16 + lrow) * AO_COLS + k0 + lcol, &As[c * 512]);
      gload_lds16(Bg + (size_t)(c*16 + lrow) * AO_COLS + k0 + lcol, &Bs[c * 512]);
    }
    __syncthreads();
    short8 af[4], bf[4];
    #pragma unroll
    for (int i = 0; i < 4; i++) af[i] = *(const short8*)&As[(wm*64 + i*16 + mcol)*32 + quad*8];
    #pragma unroll
    for (int j = 0; j < 4; j++) bf[j] = *(const short8*)&Bs[(wn*64 + j*16 + mcol)*32 + quad*8];
    #pragma unroll
    for (int i = 0; i < 4; i++)
      #pragma unroll
      for (int j = 0; j < 4; j++)
        acc[i][j] = __builtin_amdgcn_mfma_f32_16x16x32_bf16(af[i], bf[j], acc[i][j], 0, 0, 0);
    __syncthreads();
  }
  #pragma unroll
  for (int i = 0; i < 4; i++) {
    const int rb = m0 + wm*64 + i*16 + quad*4;
    #pragma unroll
    for (int j = 0; j < 4; j++) {
      const int col = n0 + wn*64 + j*16 + mcol;
      #pragma unroll
      for (int r = 0; r < 4; r++)
        Out[(size_t)(rb + r) * HID + col] = acc[i][j][r];
    }
  }
}

// ---------------------------------------------------------------------------
// Workspace layout (79,691,776 bytes total):
//   [0)          Qraw  bf16 [NH][S][HD]          8,388,608
//   [+8388608)   Kraw  bf16 [NKV][S][HD]         2,097,152
//   [+10485760)  Vt    bf16 [NKV][HD][S]         2,097,152
//   [+12582912)  AO    bf16 [S][NH*HD]           8,388,608
//   [+20971520)  Xb    bf16 [S][HID]             8,388,608
//   [+29360128)  Wqkvb bf16 [6144][4096]        50,331,648
//                Wob   bf16 [4096][4096] aliases Wqkvb (cvt after gemm_qkv)
// ---------------------------------------------------------------------------
extern "C" void kernel_launch(void* const* d_in, const int* in_sizes, int n_in,
                              void* d_out, int out_size, void* d_ws, size_t ws_size,
                              hipStream_t stream) {
  (void)in_sizes; (void)n_in; (void)out_size; (void)ws_size;
  const float* X   = (const float*)d_in[0];
  const int*   pos = (const int*)d_in[1];
  const float* Wq  = (const float*)d_in[2];
  const float* Wk  = (const float*)d_in[3];
  const float* Wv  = (const float*)d_in[4];
  const float* Wo  = (const float*)d_in[5];
  float* out = (float*)d_out;

  char* ws = (char*)d_ws;
  unsigned short* Qraw  = (unsigned short*)ws;
  unsigned short* Kraw  = (unsigned short*)(ws + 8388608);
  unsigned short* Vt    = (unsigned short*)(ws + 10485760);
  unsigned short* AO    = (unsigned short*)(ws + 12582912);
  unsigned short* Xb    = (unsigned short*)(ws + 20971520);
  unsigned short* Wqkvb = (unsigned short*)(ws + 29360128);
  unsigned short* Wob   = Wqkvb;   // alias: Wo converted after gemm_qkv reads Wqkvb

  // bf16 conversions (memory-bound; 8 elems/thread)
  cvt_k<<<dim3(2048), dim3(256), 0, stream>>>(X,  Xb);                       // 4.19M
  cvt_k<<<dim3(8192), dim3(256), 0, stream>>>(Wq, Wqkvb);                    // 16.8M
  cvt_k<<<dim3(2048), dim3(256), 0, stream>>>(Wk, Wqkvb + 16777216);         // 4.19M
  cvt_k<<<dim3(2048), dim3(256), 0, stream>>>(Wv, Wqkvb + 20971520);         // 4.19M

  gemm_qkv_k<<<dim3(48, 8),  dim3(256), 0, stream>>>(Xb, Wqkvb, Qraw, Kraw, Vt);
  rope_qk_k <<<dim3(10240),  dim3(256), 0, stream>>>(pos, Qraw, Kraw);

  cvt_k<<<dim3(8192), dim3(256), 0, stream>>>(Wo, Wob);                      // 16.8M

  attn_k    <<<dim3(64, 32), dim3(256), 0, stream>>>(Qraw, Kraw, Vt, AO);
  gemm_out_k<<<dim3(32, 8),  dim3(256), 0, stream>>>(AO, Wob, out);
}

// Round 7
// 546.969 us; speedup vs baseline: 1.8408x; 1.0628x over previous
//
#include <hip/hip_runtime.h>
#include <hip/hip_bf16.h>

// Problem constants
#define S_LEN 1024
#define HID   4096
#define NH    32
#define NKV   8
#define HD    128
#define MIN_IDX 4
#define AO_COLS 4096        // NH*HD
#define HEAD_STRIDE 131072  // S_LEN*HD

typedef __attribute__((ext_vector_type(8))) short short8;
typedef __attribute__((ext_vector_type(4))) float f32x4;

__device__ __forceinline__ unsigned short f2bf(float f) {
  union { float f; unsigned u; } v; v.f = f;
  unsigned r = v.u + 0x7FFFu + ((v.u >> 16) & 1u);   // RNE
  return (unsigned short)(r >> 16);
}
__device__ __forceinline__ float bf2f(unsigned short h) {
  union { unsigned u; float f; } v; v.u = ((unsigned)h) << 16;
  return v.f;
}
__device__ __forceinline__ unsigned pk2(float a, float b) {
  union { __hip_bfloat162 h; unsigned u; } c;
  c.h = __float22bfloat162_rn(make_float2(a, b));    // v_cvt_pk_bf16_f32
  return c.u;
}
__device__ __forceinline__ short8 pack8(float4 a, float4 b) {
  union { short8 s; unsigned u[4]; } r;
  r.u[0] = pk2(a.x, a.y); r.u[1] = pk2(a.z, a.w);
  r.u[2] = pk2(b.x, b.y); r.u[3] = pk2(b.z, b.w);
  return r.s;
}
// float -> order-preserving uint, and inverse
__device__ __forceinline__ unsigned ordf(float f) {
  union { float f; int i; } v; v.f = f;
  return (unsigned)(v.i ^ ((v.i >> 31) | 0x80000000));
}
__device__ __forceinline__ float iordf(unsigned u) {
  union { int i; float f; } v;
  v.i = (u & 0x80000000u) ? (int)(u ^ 0x80000000u) : (int)~u;
  return v.f;
}
__device__ __forceinline__ float wave_sum_f(float v) {
  #pragma unroll
  for (int m = 32; m >= 1; m >>= 1) v += __shfl_xor(v, m);
  return v;
}
__device__ __forceinline__ unsigned wave_max_u(unsigned v) {
  #pragma unroll
  for (int m = 32; m >= 1; m >>= 1) { unsigned o = __shfl_xor(v, m); v = o > v ? o : v; }
  return v;
}
// wave-local LDS fence: hist[w] is wave-private, so no block barrier needed.
__device__ __forceinline__ void wave_lds_fence() {
  __builtin_amdgcn_s_waitcnt(0);        // vmcnt(0) expcnt(0) lgkmcnt(0)
  __builtin_amdgcn_wave_barrier();      // stop compiler reordering
}
// async global->LDS, 16 B per lane. LDS dest: wave-uniform base + lane*16.
__device__ __forceinline__ void gload_lds16(const unsigned short* g, unsigned short* l) {
  auto gp = (const __attribute__((address_space(1))) unsigned*)g;
  auto lp = (__attribute__((address_space(3))) unsigned*)(unsigned)(unsigned long long)l;
  __builtin_amdgcn_global_load_lds(gp, lp, 16, 0, 0);
}

// ---------------------------------------------------------------------------
// Kernel 0: fp32 -> bf16 convert (8 elems/thread). n must be multiple of 2048.
// ---------------------------------------------------------------------------
__global__ __launch_bounds__(256) void cvt_k(
    const float* __restrict__ src, unsigned short* __restrict__ dst)
{
  const size_t i = ((size_t)blockIdx.x * 256 + threadIdx.x) * 8;
  float4 a = *(const float4*)(src + i);
  float4 b = *(const float4*)(src + i + 4);
  *(short8*)(dst + i) = pack8(a, b);
}

// ---------------------------------------------------------------------------
// Kernel 1: QKV projection (NT gemm, all-bf16, m97-style global_load_lds).
// ---------------------------------------------------------------------------
__global__ __launch_bounds__(256) void gemm_qkv_k(
    const unsigned short* __restrict__ Xb, const unsigned short* __restrict__ Wb,
    unsigned short* __restrict__ Qraw, unsigned short* __restrict__ Kraw,
    unsigned short* __restrict__ Vt)
{
  __shared__ unsigned short As[128 * 32];  // unpadded: global_load_lds layout
  __shared__ unsigned short Bs[128 * 32];
  const int nt = blockIdx.x;               // 0..47
  const int n0 = nt * 128;
  const int m0 = blockIdx.y * 128;
  const int t = threadIdx.x, w = t >> 6, lane = t & 63;
  const int wm = w >> 1, wn = w & 1;
  const int mcol = lane & 15, quad = lane >> 4;
  const int lrow = lane >> 2, lcol = (lane & 3) * 8;   // staging map (16B/lane)

  const unsigned short* Ag = Xb + (size_t)m0 * HID;
  const unsigned short* Bg = Wb + (size_t)n0 * HID;

  f32x4 acc[4][4];
  #pragma unroll
  for (int i = 0; i < 4; i++)
    #pragma unroll
    for (int j = 0; j < 4; j++) acc[i][j] = (f32x4){0.f, 0.f, 0.f, 0.f};

  for (int k0 = 0; k0 < HID; k0 += 32) {
    #pragma unroll
    for (int c2 = 0; c2 < 2; c2++) {
      const int c = w * 2 + c2;            // chunk: rows c*16..c*16+15
      gload_lds16(Ag + (size_t)(c*16 + lrow) * HID + k0 + lcol, &As[c * 512]);
      gload_lds16(Bg + (size_t)(c*16 + lrow) * HID + k0 + lcol, &Bs[c * 512]);
    }
    __syncthreads();                       // drains vmcnt -> LDS valid
    short8 af[4], bf[4];
    #pragma unroll
    for (int i = 0; i < 4; i++) af[i] = *(const short8*)&As[(wm*64 + i*16 + mcol)*32 + quad*8];
    #pragma unroll
    for (int j = 0; j < 4; j++) bf[j] = *(const short8*)&Bs[(wn*64 + j*16 + mcol)*32 + quad*8];
    #pragma unroll
    for (int i = 0; i < 4; i++)
      #pragma unroll
      for (int j = 0; j < 4; j++)
        acc[i][j] = __builtin_amdgcn_mfma_f32_16x16x32_bf16(af[i], bf[j], acc[i][j], 0, 0, 0);
    __syncthreads();
  }

  if (nt < 40) {
    unsigned short* dst = (nt < 32) ? (Qraw + (size_t)nt * HEAD_STRIDE)
                                    : (Kraw + (size_t)(nt - 32) * HEAD_STRIDE);
    #pragma unroll
    for (int i = 0; i < 4; i++) {
      const int rb = m0 + wm*64 + i*16 + quad*4;   // C/D: row=(lane>>4)*4+reg
      #pragma unroll
      for (int j = 0; j < 4; j++) {
        const int d = wn*64 + j*16 + mcol;         // col=lane&15
        #pragma unroll
        for (int r = 0; r < 4; r++)
          dst[(size_t)(rb + r) * HD + d] = f2bf(acc[i][j][r]);
      }
    }
  } else {
    unsigned short* dst = Vt + (size_t)(nt - 40) * HEAD_STRIDE;
    #pragma unroll
    for (int i = 0; i < 4; i++) {
      const int rb = m0 + wm*64 + i*16 + quad*4;   // 4 consecutive s per lane
      #pragma unroll
      for (int j = 0; j < 4; j++) {
        const int d = wn*64 + j*16 + mcol;
        ushort4 v4;
        v4.x = f2bf(acc[i][j][0]); v4.y = f2bf(acc[i][j][1]);
        v4.z = f2bf(acc[i][j][2]); v4.w = f2bf(acc[i][j][3]);
        *(ushort4*)(dst + (size_t)d * S_LEN + rb) = v4;
      }
    }
  }
}

// ---------------------------------------------------------------------------
// Kernel 2: RoPE in-place on bf16 Q and K. One wave per (head_row, s).
// ---------------------------------------------------------------------------
__global__ __launch_bounds__(256) void rope_qk_k(
    const int* __restrict__ pos_ids,
    unsigned short* __restrict__ Qraw, unsigned short* __restrict__ Kraw)
{
  const int w = threadIdx.x >> 6, lane = threadIdx.x & 63;
  const int gw = blockIdx.x * 4 + w;           // 0 .. (NH+NKV)*S-1
  const int hidx = gw >> 10;
  const int s = gw & 1023;
  const float pos = (float)pos_ids[s];
  const float invf = powf(10000.0f, -(float)lane * (1.0f / 64.0f));
  float sn, cs;
  sincosf(pos * invf, &sn, &cs);
  unsigned short* base = (hidx < NH)
      ? (Qraw + (size_t)hidx * HEAD_STRIDE + (size_t)s * HD)
      : (Kraw + (size_t)(hidx - NH) * HEAD_STRIDE + (size_t)s * HD);
  const float x0 = bf2f(base[lane]), x1 = bf2f(base[lane + 64]);
  base[lane]      = f2bf(x0 * cs - x1 * sn);
  base[lane + 64] = f2bf(x1 * cs + x0 * sn);
}

// ---------------------------------------------------------------------------
// Kernel 3: fused sparse attention, KT-specialized (KT = #128-key tiles).
//  Phase 1: per-kt scores -> double-buffered scb -> registers (1 barrier/kt).
//  Phase 2: radix-select in registers; tie_budget = final krem (invariant);
//           mx = row max (rank-1 always kept); single fused exp+write sweep
//           producing UNNORMALIZED bf16 P; 1/ssum applied in PV epilogue.
//  Phase 3: PV MFMA (P from LDS, V direct from global), epilogue scales.
// ---------------------------------------------------------------------------
#define PSTR 1040
template<int KT>
__device__ __forceinline__ void attn_body(
    const unsigned short* __restrict__ Qb, const unsigned short* __restrict__ Kh,
    const unsigned short* __restrict__ Vh, unsigned short* __restrict__ AO,
    unsigned short (*Pl)[PSTR], int (*hist)[256], float* rowinv,
    int q0, int h, int w, int lane, int mcol, int quad)
{
  constexpr int NC = 2 * KT;                   // 64-key chunks per row
  const float scale = 0.08838834764831845f;    // 1/sqrt(128)
  float (*scb)[16][130] = (float (*)[16][130])&Pl[0][0];  // 2x8320 B overlay

  short8 aq[4];
  {
    const unsigned short* qrow = Qb + ((size_t)h * S_LEN + q0 + mcol) * HD + quad * 8;
    #pragma unroll
    for (int kk = 0; kk < 4; kk++) aq[kk] = *(const short8*)(qrow + kk * 32);
  }

  unsigned su[4][NC];                          // wave-owned rows w*4..w*4+3

  // ---- Phase 1: scores -> dbuf chunk transpose -> registers ----
  #pragma unroll
  for (int kt = 0; kt < KT; kt++) {
    short8 bfr[2][4];
    #pragma unroll
    for (int g2 = 0; g2 < 2; g2++) {
      const int key = kt * 128 + (w * 2 + g2) * 16 + mcol;
      const unsigned short* krow = Kh + (size_t)key * HD + quad * 8;
      #pragma unroll
      for (int kk = 0; kk < 4; kk++) bfr[g2][kk] = *(const short8*)(krow + kk * 32);
    }
    f32x4 d4[2];
    d4[0] = (f32x4){0.f,0.f,0.f,0.f}; d4[1] = (f32x4){0.f,0.f,0.f,0.f};
    #pragma unroll
    for (int g2 = 0; g2 < 2; g2++)
      #pragma unroll
      for (int kk = 0; kk < 4; kk++)
        d4[g2] = __builtin_amdgcn_mfma_f32_16x16x32_bf16(aq[kk], bfr[g2][kk], d4[g2], 0, 0, 0);
    #pragma unroll
    for (int g2 = 0; g2 < 2; g2++) {
      const int colc = (w * 2 + g2) * 16 + mcol;
      #pragma unroll
      for (int r = 0; r < 4; r++) scb[kt & 1][quad*4 + r][colc] = d4[g2][r] * scale;
    }
    __syncthreads();
    #pragma unroll
    for (int i = 0; i < 4; i++)
      #pragma unroll
      for (int sub = 0; sub < 2; sub++)
        su[i][kt*2 + sub] = ordf(scb[kt & 1][w*4 + i][sub*64 + lane]);
  }
  __syncthreads();                             // scb dead; Pl overlay safe

  // ---- Phase 2: selection + softmax in registers ----
  #pragma unroll
  for (int i = 0; i < 4; i++) {
    const int r = w * 4 + i;
    const int q = q0 + r;
    const int L = q + 1;
    int ksel = L >> 1; if (ksel < 1) ksel = 1;

    unsigned prefix = 0, msk = 0;
    int krem = ksel;
    #pragma unroll
    for (int shift = 24; shift >= 0; shift -= 8) {
      { int4 z = {0, 0, 0, 0}; *(int4*)&hist[w][lane * 4] = z; }
      wave_lds_fence();
      #pragma unroll
      for (int c = 0; c < NC; c++) {
        const int j = c * 64 + lane;
        if (j < L && (su[i][c] & msk) == prefix)
          atomicAdd(&hist[w][(su[i][c] >> shift) & 255], 1);
      }
      wave_lds_fence();
      const int4 cv = *(const int4*)&hist[w][252 - lane * 4];
      int c4[4] = { cv.w, cv.z, cv.y, cv.x };    // descending bins
      const int lsum = c4[0] + c4[1] + c4[2] + c4[3];
      int x = lsum;
      #pragma unroll
      for (int d2 = 1; d2 < 64; d2 <<= 1) { int y = __shfl_up(x, d2); if (lane >= d2) x += y; }
      int run = x - lsum;
      int fbin = -1, fbefore = 0;
      #pragma unroll
      for (int j2 = 0; j2 < 4; j2++) {
        if (fbin < 0 && run < krem && run + c4[j2] >= krem) { fbin = 255 - lane*4 - j2; fbefore = run; }
        run += c4[j2];
      }
      unsigned long long bal = __ballot(fbin >= 0);
      int bin = 0, before = 0;
      if (bal != 0ull) {
        const int srcl = __ffsll((unsigned long long)bal) - 1;
        bin = __shfl(fbin, srcl);
        before = __shfl(fbefore, srcl);
        if (bin < 0) bin = 0;
      }
      krem -= before; if (krem < 1) krem = 1;
      prefix |= ((unsigned)bin) << shift;
      msk |= 0xFFu << shift;
    }
    const unsigned tau = prefix;
    const int tie_budget = krem;               // invariant: = ksel - #{u>tau}

    // mx = max over kept = row max (rank-1 element always kept)
    unsigned um = 0;
    #pragma unroll
    for (int c = 0; c < NC; c++) {
      const int j = c * 64 + lane;
      if (j < L && su[i][c] > um) um = su[i][c];
    }
    const float mx = iordf(wave_max_u(um));

    // fused: keep + exp + unnormalized-P write + sum
    float ssum = 0.f;
    int tiebase = 0;
    #pragma unroll
    for (int c = 0; c < NC; c++) {
      const int j = c * 64 + lane;
      const bool act = j < L;
      const unsigned u = su[i][c];
      const bool eq = act && (u == tau);
      const unsigned long long bal = __ballot(eq);
      const int trank = tiebase + (int)__popcll(bal & ((1ull << lane) - 1ull));
      tiebase += (int)__popcll(bal);
      const bool kept = act && ((u > tau) || (eq && trank < tie_budget) || (j < MIN_IDX));
      const float e = kept ? __expf(iordf(u) - mx) : 0.f;
      Pl[r][c*64 + lane] = f2bf(e);
      ssum += e;
    }
    ssum = wave_sum_f(ssum);
    if (lane == 0) rowinv[r] = 1.f / fmaxf(ssum, 1e-30f);
  }
  __syncthreads();

  // ---- Phase 3: PV (bf16 A from Pl, V direct from global) ----
  f32x4 opv[2];
  opv[0] = (f32x4){0.f,0.f,0.f,0.f}; opv[1] = (f32x4){0.f,0.f,0.f,0.f};
  #pragma unroll
  for (int kt = 0; kt < KT; kt++) {
    #pragma unroll
    for (int kb = 0; kb < 4; kb++) {
      short8 af = *(const short8*)&Pl[mcol][kt*128 + kb*32 + quad*8];
      #pragma unroll
      for (int n2 = 0; n2 < 2; n2++) {
        const int d = (w*2 + n2) * 16 + mcol;
        short8 bfr = *(const short8*)(Vh + (size_t)d * S_LEN + kt*128 + kb*32 + quad*8);
        opv[n2] = __builtin_amdgcn_mfma_f32_16x16x32_bf16(af, bfr, opv[n2], 0, 0, 0);
      }
    }
  }
  #pragma unroll
  for (int n2 = 0; n2 < 2; n2++) {
    const int col = h * HD + (w*2 + n2) * 16 + mcol;
    #pragma unroll
    for (int r2 = 0; r2 < 4; r2++) {
      const int row = q0 + quad*4 + r2;
      AO[(size_t)row * AO_COLS + col] = f2bf(opv[n2][r2] * rowinv[quad*4 + r2]);
    }
  }
}

__global__ __launch_bounds__(256, 4) void attn_k(
    const unsigned short* __restrict__ Qb, const unsigned short* __restrict__ Kb,
    const unsigned short* __restrict__ Vt, unsigned short* __restrict__ AO)
{
  __shared__ unsigned short Pl[16][PSTR];      // 33280 B
  __shared__ int hist[4][256];                 // 4096 B (wave-private rows)
  __shared__ float rowinv[16];
  const int rb = (int)gridDim.x - 1 - (int)blockIdx.x;  // heavy blocks first
  const int h = blockIdx.y;
  const int kvh = h >> 2;                      // GROUPS=4
  const int q0 = rb * 16;
  const int kt_max = (rb >> 3) + 1;            // == (q0+16+127)>>7
  const int t = threadIdx.x, w = t >> 6, lane = t & 63;
  const int mcol = lane & 15, quad = lane >> 4;
  const unsigned short* Kh = Kb + (size_t)kvh * HEAD_STRIDE;  // [s][d]
  const unsigned short* Vh = Vt + (size_t)kvh * HEAD_STRIDE;  // [d][s]

  switch (kt_max) {
    case 1: attn_body<1>(Qb, Kh, Vh, AO, Pl, hist, rowinv, q0, h, w, lane, mcol, quad); break;
    case 2: attn_body<2>(Qb, Kh, Vh, AO, Pl, hist, rowinv, q0, h, w, lane, mcol, quad); break;
    case 3: attn_body<3>(Qb, Kh, Vh, AO, Pl, hist, rowinv, q0, h, w, lane, mcol, quad); break;
    case 4: attn_body<4>(Qb, Kh, Vh, AO, Pl, hist, rowinv, q0, h, w, lane, mcol, quad); break;
    case 5: attn_body<5>(Qb, Kh, Vh, AO, Pl, hist, rowinv, q0, h, w, lane, mcol, quad); break;
    case 6: attn_body<6>(Qb, Kh, Vh, AO, Pl, hist, rowinv, q0, h, w, lane, mcol, quad); break;
    case 7: attn_body<7>(Qb, Kh, Vh, AO, Pl, hist, rowinv, q0, h, w, lane, mcol, quad); break;
    default: attn_body<8>(Qb, Kh, Vh, AO, Pl, hist, rowinv, q0, h, w, lane, mcol, quad); break;
  }
}

// ---------------------------------------------------------------------------
// Kernel 4: output projection (all-bf16, m97-style global_load_lds).
// ---------------------------------------------------------------------------
__global__ __launch_bounds__(256) void gemm_out_k(
    const unsigned short* __restrict__ A, const unsigned short* __restrict__ Wob,
    float* __restrict__ Out)
{
  __shared__ unsigned short As[128 * 32];
  __shared__ unsigned short Bs[128 * 32];
  const int n0 = blockIdx.x * 128;
  const int m0 = blockIdx.y * 128;
  const int t = threadIdx.x, w = t >> 6, lane = t & 63;
  const int wm = w >> 1, wn = w & 1;
  const int mcol = lane & 15, quad = lane >> 4;
  const int lrow = lane >> 2, lcol = (lane & 3) * 8;

  const unsigned short* Ag = A   + (size_t)m0 * AO_COLS;
  const unsigned short* Bg = Wob + (size_t)n0 * AO_COLS;

  f32x4 acc[4][4];
  #pragma unroll
  for (int i = 0; i < 4; i++)
    #pragma unroll
    for (int j = 0; j < 4; j++) acc[i][j] = (f32x4){0.f, 0.f, 0.f, 0.f};

  for (int k0 = 0; k0 < AO_COLS; k0 += 32) {
    #pragma unroll
    for (int c2 = 0; c2 < 2; c2++) {
      const int c = w * 2 + c2;
      gload_lds16(Ag + (size_t)(c*16 + lrow) * AO_COLS + k0 + lcol, &As[c * 512]);
      gload_lds16(Bg + (size_t)(c*16 + lrow) * AO_COLS + k0 + lcol, &Bs[c * 512]);
    }
    __syncthreads();
    short8 af[4], bf[4];
    #pragma unroll
    for (int i = 0; i < 4; i++) af[i] = *(const short8*)&As[(wm*64 + i*16 + mcol)*32 + quad*8];
    #pragma unroll
    for (int j = 0; j < 4; j++) bf[j] = *(const short8*)&Bs[(wn*64 + j*16 + mcol)*32 + quad*8];
    #pragma unroll
    for (int i = 0; i < 4; i++)
      #pragma unroll
      for (int j = 0; j < 4; j++)
        acc[i][j] = __builtin_amdgcn_mfma_f32_16x16x32_bf16(af[i], bf[j], acc[i][j], 0, 0, 0);
    __syncthreads();
  }
  #pragma unroll
  for (int i = 0; i < 4; i++) {
    const int rb = m0 + wm*64 + i*16 + quad*4;
    #pragma unroll
    for (int j = 0; j < 4; j++) {
      const int col = n0 + wn*64 + j*16 + mcol;
      #pragma unroll
      for (int r = 0; r < 4; r++)
        Out[(size_t)(rb + r) * HID + col] = acc[i][j][r];
    }
  }
}

// ---------------------------------------------------------------------------
// Workspace layout (79,691,776 bytes total):
//   [0)          Qraw  bf16 [NH][S][HD]          8,388,608
//   [+8388608)   Kraw  bf16 [NKV][S][HD]         2,097,152
//   [+10485760)  Vt    bf16 [NKV][HD][S]         2,097,152
//   [+12582912)  AO    bf16 [S][NH*HD]           8,388,608
//   [+20971520)  Xb    bf16 [S][HID]             8,388,608
//   [+29360128)  Wqkvb bf16 [6144][4096]        50,331,648
//                Wob   bf16 [4096][4096] aliases Wqkvb (cvt after gemm_qkv)
// ---------------------------------------------------------------------------
extern "C" void kernel_launch(void* const* d_in, const int* in_sizes, int n_in,
                              void* d_out, int out_size, void* d_ws, size_t ws_size,
                              hipStream_t stream) {
  (void)in_sizes; (void)n_in; (void)out_size; (void)ws_size;
  const float* X   = (const float*)d_in[0];
  const int*   pos = (const int*)d_in[1];
  const float* Wq  = (const float*)d_in[2];
  const float* Wk  = (const float*)d_in[3];
  const float* Wv  = (const float*)d_in[4];
  const float* Wo  = (const float*)d_in[5];
  float* out = (float*)d_out;

  char* ws = (char*)d_ws;
  unsigned short* Qraw  = (unsigned short*)ws;
  unsigned short* Kraw  = (unsigned short*)(ws + 8388608);
  unsigned short* Vt    = (unsigned short*)(ws + 10485760);
  unsigned short* AO    = (unsigned short*)(ws + 12582912);
  unsigned short* Xb    = (unsigned short*)(ws + 20971520);
  unsigned short* Wqkvb = (unsigned short*)(ws + 29360128);
  unsigned short* Wob   = Wqkvb;   // alias: Wo converted after gemm_qkv reads Wqkvb

  // bf16 conversions (memory-bound; 8 elems/thread)
  cvt_k<<<dim3(2048), dim3(256), 0, stream>>>(X,  Xb);                       // 4.19M
  cvt_k<<<dim3(8192), dim3(256), 0, stream>>>(Wq, Wqkvb);                    // 16.8M
  cvt_k<<<dim3(2048), dim3(256), 0, stream>>>(Wk, Wqkvb + 16777216);         // 4.19M
  cvt_k<<<dim3(2048), dim3(256), 0, stream>>>(Wv, Wqkvb + 20971520);         // 4.19M

  gemm_qkv_k<<<dim3(48, 8),  dim3(256), 0, stream>>>(Xb, Wqkvb, Qraw, Kraw, Vt);
  rope_qk_k <<<dim3(10240),  dim3(256), 0, stream>>>(pos, Qraw, Kraw);

  cvt_k<<<dim3(8192), dim3(256), 0, stream>>>(Wo, Wob);                      // 16.8M

  attn_k    <<<dim3(64, 32), dim3(256), 0, stream>>>(Qraw, Kraw, Vt, AO);
  gemm_out_k<<<dim3(32, 8),  dim3(256), 0, stream>>>(AO, Wob, out);
}